// Round 1
// baseline (723.353 us; speedup 1.0000x reference)
//
#include <hip/hip_runtime.h>
#include <hip/hip_bf16.h>

#define BATCH 512
#define NVERT 6890
#define NJ 24
#define NBETA 10
#define NPOSE 207

// ---------------- jts kernel: JT = Jreg@template, JS = Jreg@shapedirs ----------------
// jts[jn*33 + d*11 + 0] = sum_v Jreg[jn,v]*template[v,d]
// jts[jn*33 + d*11 + 1+s] = sum_v Jreg[jn,v]*shapedirs[v,d,s]
__global__ __launch_bounds__(256) void jts_kernel(
    const float* __restrict__ Jreg, const float* __restrict__ v_template,
    const float* __restrict__ shapedirs, float* __restrict__ jts)
{
    int jn = blockIdx.x;
    int tid = threadIdx.x;
    float p[33];
#pragma unroll
    for (int k = 0; k < 33; ++k) p[k] = 0.f;
    for (int v = tid; v < NVERT; v += 256) {
        float jr = Jreg[jn * NVERT + v];
#pragma unroll
        for (int d = 0; d < 3; ++d) {
            int gr = v * 3 + d;
            p[d * 11] += jr * v_template[gr];
#pragma unroll
            for (int s = 0; s < NBETA; ++s)
                p[d * 11 + 1 + s] += jr * shapedirs[gr * NBETA + s];
        }
    }
#pragma unroll
    for (int k = 0; k < 33; ++k) {
        float x = p[k];
        for (int off = 32; off > 0; off >>= 1) x += __shfl_down(x, off);
        p[k] = x;
    }
    if ((tid & 63) == 0) {
#pragma unroll
        for (int k = 0; k < 33; ++k) atomicAdd(&jts[jn * 33 + k], p[k]);
    }
}

// ---------------- pose kernel: Rodrigues + pose_map coefficients ----------------
__global__ __launch_bounds__(256) void pose_kernel(
    const float* __restrict__ bp, float* __restrict__ rot_ws, float* __restrict__ posecoef)
{
    int idx = blockIdx.x * 256 + threadIdx.x;
    if (idx >= BATCH * NJ) return;
    int b = idx / NJ;
    int jn = idx - b * NJ;
    float ax = bp[b * 72 + jn * 3 + 0];
    float ay = bp[b * 72 + jn * 3 + 1];
    float az = bp[b * 72 + jn * 3 + 2];
    float sx = ax + 1e-8f, sy = ay + 1e-8f, sz = az + 1e-8f;
    float angle = sqrtf(sx * sx + sy * sy + sz * sz);
    float inv = 1.f / angle;
    float ux = ax * inv, uy = ay * inv, uz = az * inv;
    float half = 0.5f * angle;
    float cw = cosf(half), sw = sinf(half);
    float qw = cw, qx = sw * ux, qy = sw * uy, qz = sw * uz;
    float qn = sqrtf(qw * qw + qx * qx + qy * qy + qz * qz);
    float qi = 1.f / qn;
    qw *= qi; qx *= qi; qy *= qi; qz *= qi;
    float w2 = qw * qw, x2 = qx * qx, y2 = qy * qy, z2 = qz * qz;
    float wx = qw * qx, wy = qw * qy, wz = qw * qz;
    float xy = qx * qy, xz = qx * qz, yz = qy * qz;
    float r[9];
    r[0] = w2 + x2 - y2 - z2; r[1] = 2.f * (xy - wz); r[2] = 2.f * (wy + xz);
    r[3] = 2.f * (wz + xy);   r[4] = w2 - x2 + y2 - z2; r[5] = 2.f * (yz - wx);
    r[6] = 2.f * (xz - wy);   r[7] = 2.f * (wx + yz);   r[8] = w2 - x2 - y2 + z2;
#pragma unroll
    for (int k = 0; k < 9; ++k) rot_ws[idx * 9 + k] = r[k];
    if (jn > 0) {
#pragma unroll
        for (int k = 0; k < 9; ++k) {
            float diag = (k == 0 || k == 4 || k == 8) ? 1.f : 0.f;
            posecoef[b * NPOSE + (jn - 1) * 9 + k] = r[k] - diag;
        }
    }
}

// ---------------- chain kernel: kinematic chain, rel_tf, jtr ----------------
__global__ __launch_bounds__(256) void chain_kernel(
    const float* __restrict__ betas, const float* __restrict__ trans,
    const float* __restrict__ rot_ws, const float* __restrict__ jts,
    float* __restrict__ relW, float* __restrict__ jtr_out)
{
    int b = blockIdx.x * 256 + threadIdx.x;
    if (b >= BATCH) return;
    constexpr int P[NJ] = {-1, 0, 0, 0, 1, 2, 3, 4, 5, 6, 7, 8, 9, 9, 9, 12, 13, 14, 16, 17, 18, 19, 20, 21};

    float be[NBETA];
#pragma unroll
    for (int s = 0; s < NBETA; ++s) be[s] = betas[b * NBETA + s];

    float jj[NJ][3];
#pragma unroll
    for (int jn = 0; jn < NJ; ++jn) {
#pragma unroll
        for (int d = 0; d < 3; ++d) {
            const float* pp = &jts[jn * 33 + d * 11];
            float a = pp[0];
#pragma unroll
            for (int s = 0; s < NBETA; ++s) a += pp[1 + s] * be[s];
            jj[jn][d] = a;
        }
    }

    const float* rotb = rot_ws + b * (NJ * 9);
    float tr0 = trans[b * 3 + 0], tr1 = trans[b * 3 + 1], tr2 = trans[b * 3 + 2];

    float res[NJ][12];  // static indexing only -> registers via liveness
    // joint 0
    {
#pragma unroll
        for (int m = 0; m < 3; ++m) {
            res[0][m * 4 + 0] = rotb[m * 3 + 0];
            res[0][m * 4 + 1] = rotb[m * 3 + 1];
            res[0][m * 4 + 2] = rotb[m * 3 + 2];
            res[0][m * 4 + 3] = jj[0][m];
        }
    }
#pragma unroll
    for (int i = 1; i < NJ; ++i) {
        const int p = P[i];
        float R[9];
#pragma unroll
        for (int k = 0; k < 9; ++k) R[k] = rotb[i * 9 + k];
        float tx = jj[i][0] - jj[p][0];
        float ty = jj[i][1] - jj[p][1];
        float tz = jj[i][2] - jj[p][2];
#pragma unroll
        for (int m = 0; m < 3; ++m) {
            float p0 = res[p][m * 4 + 0], p1 = res[p][m * 4 + 1], p2 = res[p][m * 4 + 2], p3 = res[p][m * 4 + 3];
#pragma unroll
            for (int n = 0; n < 3; ++n)
                res[i][m * 4 + n] = p0 * R[0 * 3 + n] + p1 * R[1 * 3 + n] + p2 * R[2 * 3 + n];
            res[i][m * 4 + 3] = p0 * tx + p1 * ty + p2 * tz + p3;
        }
    }
    // outputs: rel_tf and jtr
#pragma unroll
    for (int i = 0; i < NJ; ++i) {
#pragma unroll
        for (int m = 0; m < 3; ++m) {
            float r0 = res[i][m * 4 + 0], r1 = res[i][m * 4 + 1], r2 = res[i][m * 4 + 2], t = res[i][m * 4 + 3];
            float tp = t - (r0 * jj[i][0] + r1 * jj[i][1] + r2 * jj[i][2]);
            relW[(b * NJ + i) * 12 + m * 4 + 0] = r0;
            relW[(b * NJ + i) * 12 + m * 4 + 1] = r1;
            relW[(b * NJ + i) * 12 + m * 4 + 2] = r2;
            relW[(b * NJ + i) * 12 + m * 4 + 3] = tp;
            float trm = (m == 0) ? tr0 : ((m == 1) ? tr1 : tr2);
            jtr_out[(b * NJ + i) * 3 + m] = t + trm;
        }
    }
}

// ---------------- main kernel: fused pose-GEMM + skinning ----------------
// tile: 64 verts x 32 batches, 256 threads, thread = 4 verts x 2 batches
#define BKC 69
#define AST 72
#define CST 76
#define RST 292

__global__ __launch_bounds__(256) void main_kernel(
    const float* __restrict__ v_template, const float* __restrict__ shapedirs,
    const float* __restrict__ posedirs, const float* __restrict__ weights,
    const float* __restrict__ betas, const float* __restrict__ trans,
    const float* __restrict__ posecoef, const float* __restrict__ relW,
    float* __restrict__ out)
{
    __shared__ __align__(16) float smem[16256];  // 65024 B
    float* As = smem;             // [192][72]
    float* Cs = smem + 192 * AST; // [32][76]
    float* RelS = smem;           // phase2 overlay: [32][292]
    float* Wts = smem + 32 * RST; // [64][24]

    const int tid = threadIdx.x;
    const int vgrp = tid >> 4;   // 0..15 -> 4 verts each
    const int bgrp = tid & 15;   // 0..15 -> 2 batches each
    const int blockV = blockIdx.x * 64;
    const int blockB = blockIdx.y * 32;
    const int b0 = blockB + bgrp * 2;

    float be[2][NBETA];
#pragma unroll
    for (int bi = 0; bi < 2; ++bi)
#pragma unroll
        for (int s = 0; s < NBETA; ++s) be[bi][s] = betas[(b0 + bi) * NBETA + s];

    // v_shaped init: template + shapedirs @ betas
    float vp[4][2][3];
#pragma unroll
    for (int vi = 0; vi < 4; ++vi) {
        int v = blockV + vgrp * 4 + vi;
        bool valid = v < NVERT;
#pragma unroll
        for (int d = 0; d < 3; ++d) {
            int gr = v * 3 + d;
            float t = valid ? v_template[gr] : 0.f;
            float sd[NBETA];
#pragma unroll
            for (int s = 0; s < NBETA; ++s) sd[s] = valid ? shapedirs[gr * NBETA + s] : 0.f;
#pragma unroll
            for (int bi = 0; bi < 2; ++bi) {
                float a = t;
#pragma unroll
                for (int s = 0; s < NBETA; ++s) a += sd[s] * be[bi][s];
                vp[vi][bi][d] = a;
            }
        }
    }

    // K loop: v_posed += posedirs @ posecoef, 3 chunks of 69
    for (int c = 0; c < 3; ++c) {
        __syncthreads();
        for (int i = tid; i < 192 * BKC; i += 256) {
            int r = i / BKC;
            int kk = i - r * BKC;
            int gr = blockV * 3 + r;
            As[r * AST + kk] = (gr < NVERT * 3) ? posedirs[gr * NPOSE + c * BKC + kk] : 0.f;
        }
        if (tid < 192) {
            As[tid * AST + 69] = 0.f; As[tid * AST + 70] = 0.f; As[tid * AST + 71] = 0.f;
        }
        for (int i = tid; i < 32 * BKC; i += 256) {
            int lb = i / BKC;
            int kk = i - lb * BKC;
            Cs[lb * CST + kk] = posecoef[(blockB + lb) * NPOSE + c * BKC + kk];
        }
        if (tid < 32) {
            Cs[tid * CST + 69] = 0.f; Cs[tid * CST + 70] = 0.f; Cs[tid * CST + 71] = 0.f;
        }
        __syncthreads();
#pragma unroll
        for (int q = 0; q < 18; ++q) {
            float4 cc0 = *reinterpret_cast<const float4*>(&Cs[(bgrp * 2 + 0) * CST + q * 4]);
            float4 cc1 = *reinterpret_cast<const float4*>(&Cs[(bgrp * 2 + 1) * CST + q * 4]);
#pragma unroll
            for (int vi = 0; vi < 4; ++vi) {
#pragma unroll
                for (int d = 0; d < 3; ++d) {
                    float4 a = *reinterpret_cast<const float4*>(&As[(vgrp * 12 + vi * 3 + d) * AST + q * 4]);
                    vp[vi][0][d] += a.x * cc0.x + a.y * cc0.y + a.z * cc0.z + a.w * cc0.w;
                    vp[vi][1][d] += a.x * cc1.x + a.y * cc1.y + a.z * cc1.z + a.w * cc1.w;
                }
            }
        }
    }

    // skinning phase
    __syncthreads();
    for (int i = tid; i < 32 * 288; i += 256) {
        int lb = i / 288;
        int m = i - lb * 288;
        RelS[lb * RST + m] = relW[(blockB + lb) * 288 + m];
    }
    for (int i = tid; i < 64 * NJ; i += 256) {
        int lv = i / NJ;
        int j = i - lv * NJ;
        int v = blockV + lv;
        Wts[i] = (v < NVERT) ? weights[v * NJ + j] : 0.f;
    }
    __syncthreads();

    float vacc[4][2][3];
#pragma unroll
    for (int vi = 0; vi < 4; ++vi)
#pragma unroll
        for (int bi = 0; bi < 2; ++bi)
#pragma unroll
            for (int d = 0; d < 3; ++d) vacc[vi][bi][d] = 0.f;

    for (int j = 0; j < NJ; ++j) {
        float w4[4];
#pragma unroll
        for (int vi = 0; vi < 4; ++vi) w4[vi] = Wts[(vgrp * 4 + vi) * NJ + j];
#pragma unroll
        for (int bi = 0; bi < 2; ++bi) {
            int lb = bgrp * 2 + bi;
            float4 r0 = *reinterpret_cast<const float4*>(&RelS[lb * RST + j * 12 + 0]);
            float4 r1 = *reinterpret_cast<const float4*>(&RelS[lb * RST + j * 12 + 4]);
            float4 r2 = *reinterpret_cast<const float4*>(&RelS[lb * RST + j * 12 + 8]);
#pragma unroll
            for (int vi = 0; vi < 4; ++vi) {
                float x = vp[vi][bi][0], y = vp[vi][bi][1], z = vp[vi][bi][2];
                float q0 = r0.w + r0.x * x + r0.y * y + r0.z * z;
                float q1 = r1.w + r1.x * x + r1.y * y + r1.z * z;
                float q2 = r2.w + r2.x * x + r2.y * y + r2.z * z;
                vacc[vi][bi][0] += w4[vi] * q0;
                vacc[vi][bi][1] += w4[vi] * q1;
                vacc[vi][bi][2] += w4[vi] * q2;
            }
        }
    }

    // epilogue: + trans, store
#pragma unroll
    for (int bi = 0; bi < 2; ++bi) {
        int b = b0 + bi;
        float t0 = trans[b * 3 + 0], t1 = trans[b * 3 + 1], t2 = trans[b * 3 + 2];
#pragma unroll
        for (int vi = 0; vi < 4; ++vi) {
            int v = blockV + vgrp * 4 + vi;
            if (v < NVERT) {
                size_t base = ((size_t)b * NVERT + v) * 3;
                out[base + 0] = vacc[vi][bi][0] + t0;
                out[base + 1] = vacc[vi][bi][1] + t1;
                out[base + 2] = vacc[vi][bi][2] + t2;
            }
        }
    }
}

extern "C" void kernel_launch(void* const* d_in, const int* in_sizes, int n_in,
                              void* d_out, int out_size, void* d_ws, size_t ws_size,
                              hipStream_t stream) {
    const float* body_pose  = (const float*)d_in[0];
    const float* betas      = (const float*)d_in[1];
    const float* trans      = (const float*)d_in[2];
    const float* v_template = (const float*)d_in[3];
    const float* shapedirs  = (const float*)d_in[4];
    const float* posedirs   = (const float*)d_in[5];
    const float* Jreg       = (const float*)d_in[6];
    const float* weights    = (const float*)d_in[7];
    float* out = (float*)d_out;
    float* ws  = (float*)d_ws;

    float* rot_ws   = ws;                  // 512*24*9   = 110592
    float* posecoef = ws + 110592;         // 512*207    = 105984
    float* jts      = ws + 216576;         // 24*33      = 792
    float* relW     = ws + 217368;         // 512*24*12  = 147456
    float* jtr_out  = out + (size_t)BATCH * NVERT * 3;

    hipMemsetAsync(jts, 0, 792 * sizeof(float), stream);
    jts_kernel<<<NJ, 256, 0, stream>>>(Jreg, v_template, shapedirs, jts);
    pose_kernel<<<(BATCH * NJ + 255) / 256, 256, 0, stream>>>(body_pose, rot_ws, posecoef);
    chain_kernel<<<(BATCH + 255) / 256, 256, 0, stream>>>(betas, trans, rot_ws, jts, relW, jtr_out);
    main_kernel<<<dim3(108, 16), 256, 0, stream>>>(v_template, shapedirs, posedirs, weights,
                                                   betas, trans, posecoef, relW, out);
}

// Round 2
// 278.208 us; speedup vs baseline: 2.6000x; 2.6000x over previous
//
#include <hip/hip_runtime.h>

#define BATCH 512
#define NVERT 6890
#define NJ 24
#define NBETA 10
#define NPOSE 207
#define KPAD 256
#define MROW 20670      // NVERT*3
#define MPAD 20736      // 162*128

typedef __attribute__((ext_vector_type(8))) short short8;
typedef __attribute__((ext_vector_type(4))) float f32x4;
typedef __attribute__((ext_vector_type(8))) unsigned short ushort8;

static __device__ __forceinline__ unsigned short f2bf(float x) {
    union { float f; unsigned int u; } v; v.f = x;
    unsigned int r = (v.u + 0x7fffu + ((v.u >> 16) & 1u)) >> 16;
    return (unsigned short)r;
}
static __device__ __forceinline__ float bf2f(unsigned short u) {
    union { unsigned int u; float f; } v; v.u = ((unsigned int)u) << 16;
    return v.f;
}

static __device__ __forceinline__ void gload_lds16(const void* g, void* l) {
    __builtin_amdgcn_global_load_lds((const __attribute__((address_space(1))) void*)g,
                                     (__attribute__((address_space(3))) void*)l, 16, 0, 0);
}

// ---------------- jts kernel: JT = Jreg@template, JS = Jreg@shapedirs ----------------
__global__ __launch_bounds__(256) void jts_kernel(
    const float* __restrict__ Jreg, const float* __restrict__ v_template,
    const float* __restrict__ shapedirs, float* __restrict__ jts)
{
    int jn = blockIdx.x;
    int tid = threadIdx.x;
    float p[33];
#pragma unroll
    for (int k = 0; k < 33; ++k) p[k] = 0.f;
    for (int v = tid; v < NVERT; v += 256) {
        float jr = Jreg[jn * NVERT + v];
#pragma unroll
        for (int d = 0; d < 3; ++d) {
            int gr = v * 3 + d;
            p[d * 11] += jr * v_template[gr];
#pragma unroll
            for (int s = 0; s < NBETA; ++s)
                p[d * 11 + 1 + s] += jr * shapedirs[gr * NBETA + s];
        }
    }
#pragma unroll
    for (int k = 0; k < 33; ++k) {
        float x = p[k];
        for (int off = 32; off > 0; off >>= 1) x += __shfl_down(x, off);
        p[k] = x;
    }
    if ((tid & 63) == 0) {
#pragma unroll
        for (int k = 0; k < 33; ++k) atomicAdd(&jts[jn * 33 + k], p[k]);
    }
}

// ---------------- pose kernel: Rodrigues -> rot_ws + bf16 pose coeffs into Cb ----------------
__global__ __launch_bounds__(256) void pose_kernel(
    const float* __restrict__ bp, float* __restrict__ rot_ws, unsigned short* __restrict__ Cb)
{
    int idx = blockIdx.x * 256 + threadIdx.x;
    if (idx >= BATCH * NJ) return;
    int b = idx / NJ;
    int jn = idx - b * NJ;
    float ax = bp[b * 72 + jn * 3 + 0];
    float ay = bp[b * 72 + jn * 3 + 1];
    float az = bp[b * 72 + jn * 3 + 2];
    float sx = ax + 1e-8f, sy = ay + 1e-8f, sz = az + 1e-8f;
    float angle = sqrtf(sx * sx + sy * sy + sz * sz);
    float inv = 1.f / angle;
    float ux = ax * inv, uy = ay * inv, uz = az * inv;
    float half = 0.5f * angle;
    float cw = cosf(half), sw = sinf(half);
    float qw = cw, qx = sw * ux, qy = sw * uy, qz = sw * uz;
    float qn = sqrtf(qw * qw + qx * qx + qy * qy + qz * qz);
    float qi = 1.f / qn;
    qw *= qi; qx *= qi; qy *= qi; qz *= qi;
    float w2 = qw * qw, x2 = qx * qx, y2 = qy * qy, z2 = qz * qz;
    float wx = qw * qx, wy = qw * qy, wz = qw * qz;
    float xy = qx * qy, xz = qx * qz, yz = qy * qz;
    float r[9];
    r[0] = w2 + x2 - y2 - z2; r[1] = 2.f * (xy - wz); r[2] = 2.f * (wy + xz);
    r[3] = 2.f * (wz + xy);   r[4] = w2 - x2 + y2 - z2; r[5] = 2.f * (yz - wx);
    r[6] = 2.f * (xz - wy);   r[7] = 2.f * (wx + yz);   r[8] = w2 - x2 - y2 + z2;
#pragma unroll
    for (int k = 0; k < 9; ++k) rot_ws[idx * 9 + k] = r[k];
    if (jn > 0) {
#pragma unroll
        for (int k = 0; k < 9; ++k) {
            float diag = (k == 0 || k == 4 || k == 8) ? 1.f : 0.f;
            Cb[(size_t)b * KPAD + (jn - 1) * 9 + k] = f2bf(r[k] - diag);
        }
    }
}

// ---------------- convert kernel: Abf = bf16([posedirs | shapedirs | template | 0]) ----------------
__global__ __launch_bounds__(256) void convert_kernel(
    const float* __restrict__ posedirs, const float* __restrict__ shapedirs,
    const float* __restrict__ v_template, unsigned short* __restrict__ Abf)
{
    int idx = blockIdx.x * 256 + threadIdx.x;   // r*32 + kg
    int r = idx >> 5, kg = idx & 31;
    if (r >= MPAD) return;
    int k0 = kg * 8;
    ushort8 o;
#pragma unroll
    for (int e = 0; e < 8; ++e) {
        int k = k0 + e;
        float val = 0.f;
        if (r < MROW) {
            if (k < NPOSE) val = posedirs[(size_t)r * NPOSE + k];
            else if (k < NPOSE + NBETA) val = shapedirs[(size_t)r * NBETA + (k - NPOSE)];
            else if (k == NPOSE + NBETA) val = v_template[r];
        }
        o[e] = f2bf(val);
    }
    *(ushort8*)&Abf[(size_t)r * KPAD + k0] = o;
}

// ---------------- chain kernel: kinematic chain, rel_tf, jtr, Cb betas/one ----------------
__global__ __launch_bounds__(256) void chain_kernel(
    const float* __restrict__ betas, const float* __restrict__ trans,
    const float* __restrict__ rot_ws, const float* __restrict__ jts,
    float* __restrict__ relW, float* __restrict__ jtr_out, unsigned short* __restrict__ Cb)
{
    int b = blockIdx.x * 256 + threadIdx.x;
    if (b >= BATCH) return;
    constexpr int P[NJ] = {-1, 0, 0, 0, 1, 2, 3, 4, 5, 6, 7, 8, 9, 9, 9, 12, 13, 14, 16, 17, 18, 19, 20, 21};

    float be[NBETA];
#pragma unroll
    for (int s = 0; s < NBETA; ++s) be[s] = betas[b * NBETA + s];
#pragma unroll
    for (int s = 0; s < NBETA; ++s) Cb[(size_t)b * KPAD + NPOSE + s] = f2bf(be[s]);
    Cb[(size_t)b * KPAD + NPOSE + NBETA] = f2bf(1.f);

    float jj[NJ][3];
#pragma unroll
    for (int jn = 0; jn < NJ; ++jn) {
#pragma unroll
        for (int d = 0; d < 3; ++d) {
            const float* pp = &jts[jn * 33 + d * 11];
            float a = pp[0];
#pragma unroll
            for (int s = 0; s < NBETA; ++s) a += pp[1 + s] * be[s];
            jj[jn][d] = a;
        }
    }

    const float* rotb = rot_ws + b * (NJ * 9);
    float tr0 = trans[b * 3 + 0], tr1 = trans[b * 3 + 1], tr2 = trans[b * 3 + 2];

    float res[NJ][12];
    {
#pragma unroll
        for (int m = 0; m < 3; ++m) {
            res[0][m * 4 + 0] = rotb[m * 3 + 0];
            res[0][m * 4 + 1] = rotb[m * 3 + 1];
            res[0][m * 4 + 2] = rotb[m * 3 + 2];
            res[0][m * 4 + 3] = jj[0][m];
        }
    }
#pragma unroll
    for (int i = 1; i < NJ; ++i) {
        const int p = P[i];
        float R[9];
#pragma unroll
        for (int k = 0; k < 9; ++k) R[k] = rotb[i * 9 + k];
        float tx = jj[i][0] - jj[p][0];
        float ty = jj[i][1] - jj[p][1];
        float tz = jj[i][2] - jj[p][2];
#pragma unroll
        for (int m = 0; m < 3; ++m) {
            float p0 = res[p][m * 4 + 0], p1 = res[p][m * 4 + 1], p2 = res[p][m * 4 + 2], p3 = res[p][m * 4 + 3];
#pragma unroll
            for (int n = 0; n < 3; ++n)
                res[i][m * 4 + n] = p0 * R[0 * 3 + n] + p1 * R[1 * 3 + n] + p2 * R[2 * 3 + n];
            res[i][m * 4 + 3] = p0 * tx + p1 * ty + p2 * tz + p3;
        }
    }
#pragma unroll
    for (int i = 0; i < NJ; ++i) {
#pragma unroll
        for (int m = 0; m < 3; ++m) {
            float r0 = res[i][m * 4 + 0], r1 = res[i][m * 4 + 1], r2 = res[i][m * 4 + 2], t = res[i][m * 4 + 3];
            float tp = t - (r0 * jj[i][0] + r1 * jj[i][1] + r2 * jj[i][2]);
            relW[((size_t)b * NJ + i) * 12 + m * 4 + 0] = r0;
            relW[((size_t)b * NJ + i) * 12 + m * 4 + 1] = r1;
            relW[((size_t)b * NJ + i) * 12 + m * 4 + 2] = r2;
            relW[((size_t)b * NJ + i) * 12 + m * 4 + 3] = tp;
            float trm = (m == 0) ? tr0 : ((m == 1) ? tr1 : tr2);
            jtr_out[((size_t)b * NJ + i) * 3 + m] = t + trm;
        }
    }
}

// ---------------- gemm kernel: vposedT[b][vrow] = Cb @ Abf^T (bf16 MFMA) ----------------
// tile: M(batch)=128 x N(vrow)=128, BK=64, K=256 in 4 steps. 4 waves 2x2, each 64x64.
__global__ __launch_bounds__(256) void gemm_kernel(
    const unsigned short* __restrict__ Cb,   // [512][256] bf16
    const unsigned short* __restrict__ Abf,  // [20736][256] bf16
    unsigned short* __restrict__ vposedT)    // [512][20736] bf16
{
    __shared__ unsigned short sm[16384];     // As[128][64] | Bs[128][64]
    unsigned short* As = sm;
    unsigned short* Bs = sm + 8192;
    const int tid = threadIdx.x;
    const int lane = tid & 63, wid = tid >> 6;
    const int wm = wid >> 1, wn = wid & 1;
    const int lr = lane & 15, h = lane >> 4;
    const int Nbase = blockIdx.x * 128;   // vrow
    const int Mbase = blockIdx.y * 128;   // batch
    const int srow = lane >> 3;           // 0..7 row within staging instr
    const int schunk = lane & 7;          // dest 16B-chunk within row

    f32x4 acc[4][4];
#pragma unroll
    for (int mi = 0; mi < 4; ++mi)
#pragma unroll
        for (int ni = 0; ni < 4; ++ni) acc[mi][ni] = f32x4{0.f, 0.f, 0.f, 0.f};

    for (int ks = 0; ks < 4; ++ks) {
        __syncthreads();
        // stage A (batch/Cb) and B (vrow/Abf) tiles; source pre-swizzled so that
        // LDS slot (row, c) holds original k-chunk c ^ (row&7)  [involution]
#pragma unroll
        for (int q = 0; q < 4; ++q) {
            int rowl = wid * 32 + q * 8 + srow;
            int sc = schunk ^ (rowl & 7);
            const unsigned short* gc = &Cb[(size_t)(Mbase + rowl) * KPAD + ks * 64 + sc * 8];
            const unsigned short* ga = &Abf[(size_t)(Nbase + rowl) * KPAD + ks * 64 + sc * 8];
            gload_lds16(gc, (char*)As + wid * 4096 + q * 1024);
            gload_lds16(ga, (char*)Bs + wid * 4096 + q * 1024);
        }
        __syncthreads();
#pragma unroll
        for (int kk = 0; kk < 2; ++kk) {
            short8 a[4], b[4];
#pragma unroll
            for (int mi = 0; mi < 4; ++mi) {
                int row = wm * 64 + mi * 16 + lr;
                int ch = (kk * 4 + h) ^ (row & 7);
                a[mi] = *(const short8*)&As[row * 64 + ch * 8];
            }
#pragma unroll
            for (int ni = 0; ni < 4; ++ni) {
                int row = wn * 64 + ni * 16 + lr;
                int ch = (kk * 4 + h) ^ (row & 7);
                b[ni] = *(const short8*)&Bs[row * 64 + ch * 8];
            }
#pragma unroll
            for (int mi = 0; mi < 4; ++mi)
#pragma unroll
                for (int ni = 0; ni < 4; ++ni)
                    acc[mi][ni] = __builtin_amdgcn_mfma_f32_16x16x32_bf16(a[mi], b[ni], acc[mi][ni], 0, 0, 0);
        }
    }
    // epilogue: C/D layout col=lane&15, row=(lane>>4)*4+reg
#pragma unroll
    for (int mi = 0; mi < 4; ++mi) {
#pragma unroll
        for (int ni = 0; ni < 4; ++ni) {
            int vr = Nbase + wn * 64 + ni * 16 + lr;
#pragma unroll
            for (int r = 0; r < 4; ++r) {
                int bb = Mbase + wm * 64 + mi * 16 + h * 4 + r;
                vposedT[(size_t)bb * MPAD + vr] = f2bf(acc[mi][ni][r]);
            }
        }
    }
}

// ---------------- skin kernel: verts = LBS(vposed, rel_tf, weights) + trans ----------------
// tile 128 v x 16 b, 256 threads, thread = 8v x 1b
__global__ __launch_bounds__(256) void skin_kernel(
    const unsigned short* __restrict__ vposedT,  // [512][20736] bf16, col = v*3+d
    const float* __restrict__ relW,              // [512][288]
    const float* __restrict__ weights,           // [V][24]
    const float* __restrict__ trans,
    float* __restrict__ out)
{
    __shared__ float RelS[16 * 292];
    __shared__ float WtsT[24 * 132];
    const int tid = threadIdx.x;
    const int vgrp = tid & 15, bgrp = tid >> 4;
    const int Vbase = blockIdx.x * 128;
    const int Bbase = blockIdx.y * 16;
    const int b = Bbase + bgrp;

    for (int i = tid; i < 16 * 288; i += 256) {
        int lb = i / 288, m = i - lb * 288;
        RelS[lb * 292 + m] = relW[(size_t)(Bbase + lb) * 288 + m];
    }
    for (int i = tid; i < 24 * 128; i += 256) {
        int vl = i / 24, j = i - vl * 24;
        int v = Vbase + vl;
        WtsT[j * 132 + vl] = (v < NVERT) ? weights[v * NJ + j] : 0.f;
    }
    __syncthreads();

    // vposed for 8 verts x 3 dims: 48B contiguous per lane
    float vp[8][3];
    {
        const ushort8* p = (const ushort8*)&vposedT[(size_t)b * MPAD + Vbase * 3 + vgrp * 24];
        ushort8 c0 = p[0], c1 = p[1], c2 = p[2];
        unsigned short uu[24];
#pragma unroll
        for (int e = 0; e < 8; ++e) { uu[e] = c0[e]; uu[8 + e] = c1[e]; uu[16 + e] = c2[e]; }
#pragma unroll
        for (int n = 0; n < 24; ++n) vp[n / 3][n % 3] = bf2f(uu[n]);
    }

    float acc[8][3];
#pragma unroll
    for (int vi = 0; vi < 8; ++vi) { acc[vi][0] = 0.f; acc[vi][1] = 0.f; acc[vi][2] = 0.f; }

    const float* rb = &RelS[bgrp * 292];
#pragma unroll
    for (int j = 0; j < NJ; ++j) {
        float4 r0 = *(const float4*)&rb[j * 12 + 0];
        float4 r1 = *(const float4*)&rb[j * 12 + 4];
        float4 r2 = *(const float4*)&rb[j * 12 + 8];
        float4 w0 = *(const float4*)&WtsT[j * 132 + vgrp * 8];
        float4 w1 = *(const float4*)&WtsT[j * 132 + vgrp * 8 + 4];
        float w8[8] = {w0.x, w0.y, w0.z, w0.w, w1.x, w1.y, w1.z, w1.w};
#pragma unroll
        for (int vi = 0; vi < 8; ++vi) {
            float x = vp[vi][0], y = vp[vi][1], z = vp[vi][2];
            float q0 = fmaf(r0.x, x, fmaf(r0.y, y, fmaf(r0.z, z, r0.w)));
            float q1 = fmaf(r1.x, x, fmaf(r1.y, y, fmaf(r1.z, z, r1.w)));
            float q2 = fmaf(r2.x, x, fmaf(r2.y, y, fmaf(r2.z, z, r2.w)));
            acc[vi][0] = fmaf(w8[vi], q0, acc[vi][0]);
            acc[vi][1] = fmaf(w8[vi], q1, acc[vi][1]);
            acc[vi][2] = fmaf(w8[vi], q2, acc[vi][2]);
        }
    }

    float t0 = trans[b * 3 + 0], t1 = trans[b * 3 + 1], t2 = trans[b * 3 + 2];
#pragma unroll
    for (int vi = 0; vi < 8; ++vi) {
        int v = Vbase + vgrp * 8 + vi;
        if (v < NVERT) {
            size_t base = ((size_t)b * NVERT + v) * 3;
            out[base + 0] = acc[vi][0] + t0;
            out[base + 1] = acc[vi][1] + t1;
            out[base + 2] = acc[vi][2] + t2;
        }
    }
}

extern "C" void kernel_launch(void* const* d_in, const int* in_sizes, int n_in,
                              void* d_out, int out_size, void* d_ws, size_t ws_size,
                              hipStream_t stream) {
    const float* body_pose  = (const float*)d_in[0];
    const float* betas      = (const float*)d_in[1];
    const float* trans      = (const float*)d_in[2];
    const float* v_template = (const float*)d_in[3];
    const float* shapedirs  = (const float*)d_in[4];
    const float* posedirs   = (const float*)d_in[5];
    const float* Jreg       = (const float*)d_in[6];
    const float* weights    = (const float*)d_in[7];
    float* out = (float*)d_out;
    char* base = (char*)d_ws;

    size_t off = 0;
    auto alloc = [&](size_t bytes) { char* p = base + off; off = (off + bytes + 255) & ~(size_t)255; return p; };
    float* rot_ws            = (float*)alloc(442368);                 // 512*24*9 f32
    float* jts               = (float*)alloc(792 * 4);                // 24*33 f32
    float* relW              = (float*)alloc((size_t)BATCH * 288 * 4);
    unsigned short* Cb       = (unsigned short*)alloc((size_t)BATCH * KPAD * 2);
    unsigned short* Abf      = (unsigned short*)alloc((size_t)MPAD * KPAD * 2);
    unsigned short* vposedT  = (unsigned short*)alloc((size_t)BATCH * MPAD * 2);
    float* jtr_out = out + (size_t)BATCH * NVERT * 3;

    hipMemsetAsync(jts, 0, 792 * sizeof(float), stream);
    hipMemsetAsync(Cb, 0, (size_t)BATCH * KPAD * 2, stream);

    jts_kernel<<<NJ, 256, 0, stream>>>(Jreg, v_template, shapedirs, jts);
    pose_kernel<<<(BATCH * NJ + 255) / 256, 256, 0, stream>>>(body_pose, rot_ws, Cb);
    convert_kernel<<<(MPAD * 32) / 256, 256, 0, stream>>>(posedirs, shapedirs, v_template, Abf);
    chain_kernel<<<(BATCH + 255) / 256, 256, 0, stream>>>(betas, trans, rot_ws, jts, relW, jtr_out, Cb);
    gemm_kernel<<<dim3(MPAD / 128, BATCH / 128), 256, 0, stream>>>(Cb, Abf, vposedT);
    skin_kernel<<<dim3(54, BATCH / 16), 256, 0, stream>>>(vposedT, relW, weights, trans, out);
}

// Round 3
// 220.280 us; speedup vs baseline: 3.2838x; 1.2630x over previous
//
#include <hip/hip_runtime.h>

#define BATCH 512
#define NVERT 6890
#define NJ 24
#define NBETA 10
#define NPOSE 207
#define KPAD 256
#define MROW 20670      // NVERT*3
#define MPAD 20736      // 162*128

typedef __attribute__((ext_vector_type(8))) short short8;
typedef __attribute__((ext_vector_type(4))) float f32x4;
typedef __attribute__((ext_vector_type(8))) unsigned short ushort8;

static __device__ __forceinline__ unsigned short f2bf(float x) {
    union { float f; unsigned int u; } v; v.f = x;
    unsigned int r = (v.u + 0x7fffu + ((v.u >> 16) & 1u)) >> 16;
    return (unsigned short)r;
}
static __device__ __forceinline__ float bf2f(unsigned short u) {
    union { unsigned int u; float f; } v; v.u = ((unsigned int)u) << 16;
    return v.f;
}

static __device__ __forceinline__ void gload_lds16(const void* g, void* l) {
    __builtin_amdgcn_global_load_lds((const __attribute__((address_space(1))) void*)g,
                                     (__attribute__((address_space(3))) void*)l, 16, 0, 0);
}

// ---------------- jts kernel: JT/JS = Jreg @ [template|shapedirs], contiguous per-v loads ----------------
// grid (24 joints, 8 v-chunks); thread owns vertices Vstart+tid, step 256
__global__ __launch_bounds__(256) void jts_kernel(
    const float* __restrict__ Jreg, const float* __restrict__ v_template,
    const float* __restrict__ shapedirs, float* __restrict__ jts)
{
    const int jn = blockIdx.x;
    const int Vstart = blockIdx.y * 864;
    const int Vend = min(Vstart + 864, NVERT);
    const int tid = threadIdx.x;

    float p[33];
#pragma unroll
    for (int k = 0; k < 33; ++k) p[k] = 0.f;

    for (int v = Vstart + tid; v < Vend; v += 256) {
        float jr = Jreg[jn * NVERT + v];
        // template: 3 contiguous floats per v
        float t0 = v_template[v * 3 + 0];
        float t1 = v_template[v * 3 + 1];
        float t2 = v_template[v * 3 + 2];
        p[0]  = fmaf(jr, t0, p[0]);
        p[11] = fmaf(jr, t1, p[11]);
        p[22] = fmaf(jr, t2, p[22]);
        // shapedirs: 30 contiguous floats per v
        const float* sb = shapedirs + (size_t)v * 30;
        float sd[30];
#pragma unroll
        for (int q = 0; q < 7; ++q) {
            float4 f = *(const float4*)(sb + q * 4);
            sd[q * 4 + 0] = f.x; sd[q * 4 + 1] = f.y; sd[q * 4 + 2] = f.z; sd[q * 4 + 3] = f.w;
        }
        sd[28] = sb[28]; sd[29] = sb[29];
#pragma unroll
        for (int d = 0; d < 3; ++d)
#pragma unroll
            for (int s = 0; s < NBETA; ++s)
                p[d * 11 + 1 + s] = fmaf(jr, sd[d * 10 + s], p[d * 11 + 1 + s]);
    }
#pragma unroll
    for (int k = 0; k < 33; ++k) {
        float x = p[k];
        for (int off = 32; off > 0; off >>= 1) x += __shfl_down(x, off);
        p[k] = x;
    }
    if ((tid & 63) == 0) {
#pragma unroll
        for (int k = 0; k < 33; ++k) atomicAdd(&jts[jn * 33 + k], p[k]);
    }
}

// ---------------- pose kernel: Rodrigues -> rot_ws + bf16 pose coeffs into Cb ----------------
__global__ __launch_bounds__(256) void pose_kernel(
    const float* __restrict__ bp, float* __restrict__ rot_ws, unsigned short* __restrict__ Cb)
{
    int idx = blockIdx.x * 256 + threadIdx.x;
    if (idx >= BATCH * NJ) return;
    int b = idx / NJ;
    int jn = idx - b * NJ;
    float ax = bp[b * 72 + jn * 3 + 0];
    float ay = bp[b * 72 + jn * 3 + 1];
    float az = bp[b * 72 + jn * 3 + 2];
    float sx = ax + 1e-8f, sy = ay + 1e-8f, sz = az + 1e-8f;
    float angle = sqrtf(sx * sx + sy * sy + sz * sz);
    float inv = 1.f / angle;
    float ux = ax * inv, uy = ay * inv, uz = az * inv;
    float half = 0.5f * angle;
    float cw = cosf(half), sw = sinf(half);
    float qw = cw, qx = sw * ux, qy = sw * uy, qz = sw * uz;
    float qn = sqrtf(qw * qw + qx * qx + qy * qy + qz * qz);
    float qi = 1.f / qn;
    qw *= qi; qx *= qi; qy *= qi; qz *= qi;
    float w2 = qw * qw, x2 = qx * qx, y2 = qy * qy, z2 = qz * qz;
    float wx = qw * qx, wy = qw * qy, wz = qw * qz;
    float xy = qx * qy, xz = qx * qz, yz = qy * qz;
    float r[9];
    r[0] = w2 + x2 - y2 - z2; r[1] = 2.f * (xy - wz); r[2] = 2.f * (wy + xz);
    r[3] = 2.f * (wz + xy);   r[4] = w2 - x2 + y2 - z2; r[5] = 2.f * (yz - wx);
    r[6] = 2.f * (xz - wy);   r[7] = 2.f * (wx + yz);   r[8] = w2 - x2 - y2 + z2;
#pragma unroll
    for (int k = 0; k < 9; ++k) rot_ws[idx * 9 + k] = r[k];
    if (jn > 0) {
#pragma unroll
        for (int k = 0; k < 9; ++k) {
            float diag = (k == 0 || k == 4 || k == 8) ? 1.f : 0.f;
            Cb[(size_t)b * KPAD + (jn - 1) * 9 + k] = f2bf(r[k] - diag);
        }
    }
}

// ---------------- convert kernel: Abf = bf16([posedirs | shapedirs | template | 0]) ----------------
__global__ __launch_bounds__(256) void convert_kernel(
    const float* __restrict__ posedirs, const float* __restrict__ shapedirs,
    const float* __restrict__ v_template, unsigned short* __restrict__ Abf)
{
    int idx = blockIdx.x * 256 + threadIdx.x;   // r*32 + kg
    int r = idx >> 5, kg = idx & 31;
    if (r >= MPAD) return;
    int k0 = kg * 8;
    ushort8 o;
#pragma unroll
    for (int e = 0; e < 8; ++e) {
        int k = k0 + e;
        float val = 0.f;
        if (r < MROW) {
            if (k < NPOSE) val = posedirs[(size_t)r * NPOSE + k];
            else if (k < NPOSE + NBETA) val = shapedirs[(size_t)r * NBETA + (k - NPOSE)];
            else if (k == NPOSE + NBETA) val = v_template[r];
        }
        o[e] = f2bf(val);
    }
    *(ushort8*)&Abf[(size_t)r * KPAD + k0] = o;
}

// ---------------- chain kernel: kinematic chain, rel_tf, jtr, Cb betas/one ----------------
__global__ __launch_bounds__(256) void chain_kernel(
    const float* __restrict__ betas, const float* __restrict__ trans,
    const float* __restrict__ rot_ws, const float* __restrict__ jts,
    float* __restrict__ relW, float* __restrict__ jtr_out, unsigned short* __restrict__ Cb)
{
    int b = blockIdx.x * 256 + threadIdx.x;
    if (b >= BATCH) return;
    constexpr int P[NJ] = {-1, 0, 0, 0, 1, 2, 3, 4, 5, 6, 7, 8, 9, 9, 9, 12, 13, 14, 16, 17, 18, 19, 20, 21};

    float be[NBETA];
#pragma unroll
    for (int s = 0; s < NBETA; ++s) be[s] = betas[b * NBETA + s];
#pragma unroll
    for (int s = 0; s < NBETA; ++s) Cb[(size_t)b * KPAD + NPOSE + s] = f2bf(be[s]);
    Cb[(size_t)b * KPAD + NPOSE + NBETA] = f2bf(1.f);

    float jj[NJ][3];
#pragma unroll
    for (int jn = 0; jn < NJ; ++jn) {
#pragma unroll
        for (int d = 0; d < 3; ++d) {
            const float* pp = &jts[jn * 33 + d * 11];
            float a = pp[0];
#pragma unroll
            for (int s = 0; s < NBETA; ++s) a += pp[1 + s] * be[s];
            jj[jn][d] = a;
        }
    }

    const float* rotb = rot_ws + b * (NJ * 9);
    float tr0 = trans[b * 3 + 0], tr1 = trans[b * 3 + 1], tr2 = trans[b * 3 + 2];

    float res[NJ][12];
    {
#pragma unroll
        for (int m = 0; m < 3; ++m) {
            res[0][m * 4 + 0] = rotb[m * 3 + 0];
            res[0][m * 4 + 1] = rotb[m * 3 + 1];
            res[0][m * 4 + 2] = rotb[m * 3 + 2];
            res[0][m * 4 + 3] = jj[0][m];
        }
    }
#pragma unroll
    for (int i = 1; i < NJ; ++i) {
        const int p = P[i];
        float R[9];
#pragma unroll
        for (int k = 0; k < 9; ++k) R[k] = rotb[i * 9 + k];
        float tx = jj[i][0] - jj[p][0];
        float ty = jj[i][1] - jj[p][1];
        float tz = jj[i][2] - jj[p][2];
#pragma unroll
        for (int m = 0; m < 3; ++m) {
            float p0 = res[p][m * 4 + 0], p1 = res[p][m * 4 + 1], p2 = res[p][m * 4 + 2], p3 = res[p][m * 4 + 3];
#pragma unroll
            for (int n = 0; n < 3; ++n)
                res[i][m * 4 + n] = p0 * R[0 * 3 + n] + p1 * R[1 * 3 + n] + p2 * R[2 * 3 + n];
            res[i][m * 4 + 3] = p0 * tx + p1 * ty + p2 * tz + p3;
        }
    }
#pragma unroll
    for (int i = 0; i < NJ; ++i) {
#pragma unroll
        for (int m = 0; m < 3; ++m) {
            float r0 = res[i][m * 4 + 0], r1 = res[i][m * 4 + 1], r2 = res[i][m * 4 + 2], t = res[i][m * 4 + 3];
            float tp = t - (r0 * jj[i][0] + r1 * jj[i][1] + r2 * jj[i][2]);
            relW[((size_t)b * NJ + i) * 12 + m * 4 + 0] = r0;
            relW[((size_t)b * NJ + i) * 12 + m * 4 + 1] = r1;
            relW[((size_t)b * NJ + i) * 12 + m * 4 + 2] = r2;
            relW[((size_t)b * NJ + i) * 12 + m * 4 + 3] = tp;
            float trm = (m == 0) ? tr0 : ((m == 1) ? tr1 : tr2);
            jtr_out[((size_t)b * NJ + i) * 3 + m] = t + trm;
        }
    }
}

// ---------------- gemm kernel: vposedT[b][vrow] = Cb @ Abf^T (bf16 MFMA) ----------------
__global__ __launch_bounds__(256) void gemm_kernel(
    const unsigned short* __restrict__ Cb,   // [512][256] bf16
    const unsigned short* __restrict__ Abf,  // [20736][256] bf16
    unsigned short* __restrict__ vposedT)    // [512][20736] bf16
{
    __shared__ unsigned short sm[16384];     // As[128][64] | Bs[128][64]
    unsigned short* As = sm;
    unsigned short* Bs = sm + 8192;
    const int tid = threadIdx.x;
    const int lane = tid & 63, wid = tid >> 6;
    const int wm = wid >> 1, wn = wid & 1;
    const int lr = lane & 15, h = lane >> 4;
    const int Nbase = blockIdx.x * 128;   // vrow
    const int Mbase = blockIdx.y * 128;   // batch
    const int srow = lane >> 3;
    const int schunk = lane & 7;

    f32x4 acc[4][4];
#pragma unroll
    for (int mi = 0; mi < 4; ++mi)
#pragma unroll
        for (int ni = 0; ni < 4; ++ni) acc[mi][ni] = f32x4{0.f, 0.f, 0.f, 0.f};

    for (int ks = 0; ks < 4; ++ks) {
        __syncthreads();
#pragma unroll
        for (int q = 0; q < 4; ++q) {
            int rowl = wid * 32 + q * 8 + srow;
            int sc = schunk ^ (rowl & 7);
            const unsigned short* gc = &Cb[(size_t)(Mbase + rowl) * KPAD + ks * 64 + sc * 8];
            const unsigned short* ga = &Abf[(size_t)(Nbase + rowl) * KPAD + ks * 64 + sc * 8];
            gload_lds16(gc, (char*)As + wid * 4096 + q * 1024);
            gload_lds16(ga, (char*)Bs + wid * 4096 + q * 1024);
        }
        __syncthreads();
#pragma unroll
        for (int kk = 0; kk < 2; ++kk) {
            short8 a[4], b[4];
#pragma unroll
            for (int mi = 0; mi < 4; ++mi) {
                int row = wm * 64 + mi * 16 + lr;
                int ch = (kk * 4 + h) ^ (row & 7);
                a[mi] = *(const short8*)&As[row * 64 + ch * 8];
            }
#pragma unroll
            for (int ni = 0; ni < 4; ++ni) {
                int row = wn * 64 + ni * 16 + lr;
                int ch = (kk * 4 + h) ^ (row & 7);
                b[ni] = *(const short8*)&Bs[row * 64 + ch * 8];
            }
#pragma unroll
            for (int mi = 0; mi < 4; ++mi)
#pragma unroll
                for (int ni = 0; ni < 4; ++ni)
                    acc[mi][ni] = __builtin_amdgcn_mfma_f32_16x16x32_bf16(a[mi], b[ni], acc[mi][ni], 0, 0, 0);
        }
    }
#pragma unroll
    for (int mi = 0; mi < 4; ++mi) {
#pragma unroll
        for (int ni = 0; ni < 4; ++ni) {
            int vr = Nbase + wn * 64 + ni * 16 + lr;
#pragma unroll
            for (int r = 0; r < 4; ++r) {
                int bb = Mbase + wm * 64 + mi * 16 + h * 4 + r;
                vposedT[(size_t)bb * MPAD + vr] = f2bf(acc[mi][ni][r]);
            }
        }
    }
}

// ---------------- skin kernel v3: thread = (v,b); 64v x 4b per block ----------------
__global__ __launch_bounds__(256) void skin_kernel(
    const unsigned short* __restrict__ vposedT,  // [512][20736] bf16, col = v*3+d
    const float* __restrict__ relW,              // [512][288]
    const float* __restrict__ weights,           // [V][24]
    const float* __restrict__ trans,
    float* __restrict__ out)
{
    __shared__ float WtsT[24 * 65];
    const int tid = threadIdx.x;
    const int vl = tid & 63, bl = tid >> 6;
    const int Vbase = blockIdx.x * 64;
    const int b = blockIdx.y * 4 + bl;
    const int v = Vbase + vl;

    // stage weights transposed: global coalesced, LDS stride-65 (conflict-free)
    for (int i = tid; i < 64 * 24; i += 256) {
        int lv = i / 24;
        int j = i - lv * 24;
        int gv = Vbase + lv;
        WtsT[j * 65 + lv] = (gv < NVERT) ? weights[(size_t)gv * NJ + j] : 0.f;
    }
    __syncthreads();

    float w[NJ];
#pragma unroll
    for (int j = 0; j < NJ; ++j) w[j] = WtsT[j * 65 + vl];

    // vposed: 3 bf16 loads (contiguous 6B/lane)
    const unsigned short* vpp = vposedT + (size_t)b * MPAD + (size_t)v * 3;
    float x = bf2f(vpp[0]), y = bf2f(vpp[1]), z = bf2f(vpp[2]);

    // rel_tf via wave-uniform scalar loads
    const int bu = __builtin_amdgcn_readfirstlane(b);
    const float* rb = relW + (size_t)bu * 288;

    float a0 = 0.f, a1 = 0.f, a2 = 0.f;
#pragma unroll
    for (int j = 0; j < NJ; ++j) {
        float4 r0 = *(const float4*)(rb + j * 12 + 0);
        float4 r1 = *(const float4*)(rb + j * 12 + 4);
        float4 r2 = *(const float4*)(rb + j * 12 + 8);
        float q0 = fmaf(r0.x, x, fmaf(r0.y, y, fmaf(r0.z, z, r0.w)));
        float q1 = fmaf(r1.x, x, fmaf(r1.y, y, fmaf(r1.z, z, r1.w)));
        float q2 = fmaf(r2.x, x, fmaf(r2.y, y, fmaf(r2.z, z, r2.w)));
        a0 = fmaf(w[j], q0, a0);
        a1 = fmaf(w[j], q1, a1);
        a2 = fmaf(w[j], q2, a2);
    }

    float t0 = relW == nullptr ? 0.f : trans[bu * 3 + 0];
    float t1 = trans[bu * 3 + 1];
    float t2 = trans[bu * 3 + 2];
    if (v < NVERT) {
        size_t base = ((size_t)b * NVERT + v) * 3;
        out[base + 0] = a0 + t0;
        out[base + 1] = a1 + t1;
        out[base + 2] = a2 + t2;
    }
}

extern "C" void kernel_launch(void* const* d_in, const int* in_sizes, int n_in,
                              void* d_out, int out_size, void* d_ws, size_t ws_size,
                              hipStream_t stream) {
    const float* body_pose  = (const float*)d_in[0];
    const float* betas      = (const float*)d_in[1];
    const float* trans      = (const float*)d_in[2];
    const float* v_template = (const float*)d_in[3];
    const float* shapedirs  = (const float*)d_in[4];
    const float* posedirs   = (const float*)d_in[5];
    const float* Jreg       = (const float*)d_in[6];
    const float* weights    = (const float*)d_in[7];
    float* out = (float*)d_out;
    char* base = (char*)d_ws;

    size_t off = 0;
    auto alloc = [&](size_t bytes) { char* p = base + off; off = (off + bytes + 255) & ~(size_t)255; return p; };
    float* rot_ws            = (float*)alloc(442368);                 // 512*24*9 f32
    float* jts               = (float*)alloc(792 * 4);                // 24*33 f32
    float* relW              = (float*)alloc((size_t)BATCH * 288 * 4);
    unsigned short* Cb       = (unsigned short*)alloc((size_t)BATCH * KPAD * 2);
    unsigned short* Abf      = (unsigned short*)alloc((size_t)MPAD * KPAD * 2);
    unsigned short* vposedT  = (unsigned short*)alloc((size_t)BATCH * MPAD * 2);
    float* jtr_out = out + (size_t)BATCH * NVERT * 3;

    hipMemsetAsync(jts, 0, 792 * sizeof(float), stream);
    hipMemsetAsync(Cb, 0, (size_t)BATCH * KPAD * 2, stream);

    jts_kernel<<<dim3(NJ, 8), 256, 0, stream>>>(Jreg, v_template, shapedirs, jts);
    pose_kernel<<<(BATCH * NJ + 255) / 256, 256, 0, stream>>>(body_pose, rot_ws, Cb);
    convert_kernel<<<(MPAD * 32) / 256, 256, 0, stream>>>(posedirs, shapedirs, v_template, Abf);
    chain_kernel<<<(BATCH + 255) / 256, 256, 0, stream>>>(betas, trans, rot_ws, jts, relW, jtr_out, Cb);
    gemm_kernel<<<dim3(MPAD / 128, BATCH / 128), 256, 0, stream>>>(Cb, Abf, vposedT);
    skin_kernel<<<dim3(108, BATCH / 4), 256, 0, stream>>>(vposedT, relW, weights, trans, out);
}

// Round 4
// 174.249 us; speedup vs baseline: 4.1513x; 1.2642x over previous
//
#include <hip/hip_runtime.h>

#define BATCH 512
#define NVERT 6890
#define NJ 24
#define NBETA 10
#define NPOSE 207
#define KPAD 256
#define MROW 20670      // NVERT*3
#define MPAD 20736      // 162*128
#define VT_TILES 431    // ceil(NVERT/16)
#define VPAD16 6896     // VT_TILES*16

typedef __attribute__((ext_vector_type(8))) short short8;
typedef __attribute__((ext_vector_type(4))) float f32x4;
typedef __attribute__((ext_vector_type(8))) unsigned short ushort8;

static __device__ __forceinline__ unsigned short f2bf(float x) {
    union { float f; unsigned int u; } v; v.f = x;
    unsigned int r = (v.u + 0x7fffu + ((v.u >> 16) & 1u)) >> 16;
    return (unsigned short)r;
}
static __device__ __forceinline__ float bf2f(unsigned short u) {
    union { unsigned int u; float f; } v; v.u = ((unsigned int)u) << 16;
    return v.f;
}
static __device__ __forceinline__ void gload_lds16(const void* g, void* l) {
    __builtin_amdgcn_global_load_lds((const __attribute__((address_space(1))) void*)g,
                                     (__attribute__((address_space(3))) void*)l, 16, 0, 0);
}

// ================= prep kernel: jts | pose | convert(Abf + wT), branch on blockIdx =================
#define JTS_BLOCKS 192
#define POSE_BLOCKS 48
#define CONV_BLOCKS 2700   // 2592 Abf + 108 weightsT

__global__ __launch_bounds__(256) void prep_kernel(
    const float* __restrict__ Jreg, const float* __restrict__ v_template,
    const float* __restrict__ shapedirs, const float* __restrict__ posedirs,
    const float* __restrict__ weights, const float* __restrict__ body_pose,
    float* __restrict__ jts, float* __restrict__ rotT,
    unsigned short* __restrict__ Cb, unsigned short* __restrict__ Abf,
    unsigned short* __restrict__ wT)
{
    const int bx = blockIdx.x;
    const int tid = threadIdx.x;

    if (bx < JTS_BLOCKS) {
        // ---- jts: JT/JS = Jreg @ [template|shapedirs] ----
        const int jn = bx >> 3;
        const int Vstart = (bx & 7) * 864;
        const int Vend = min(Vstart + 864, NVERT);
        float p[33];
#pragma unroll
        for (int k = 0; k < 33; ++k) p[k] = 0.f;
        for (int v = Vstart + tid; v < Vend; v += 256) {
            float jr = Jreg[jn * NVERT + v];
            p[0]  = fmaf(jr, v_template[v * 3 + 0], p[0]);
            p[11] = fmaf(jr, v_template[v * 3 + 1], p[11]);
            p[22] = fmaf(jr, v_template[v * 3 + 2], p[22]);
            const float* sb = shapedirs + (size_t)v * 30;
            float sd[30];
#pragma unroll
            for (int q = 0; q < 7; ++q) {
                float4 f = *(const float4*)(sb + q * 4);
                sd[q * 4 + 0] = f.x; sd[q * 4 + 1] = f.y; sd[q * 4 + 2] = f.z; sd[q * 4 + 3] = f.w;
            }
            sd[28] = sb[28]; sd[29] = sb[29];
#pragma unroll
            for (int d = 0; d < 3; ++d)
#pragma unroll
                for (int s = 0; s < NBETA; ++s)
                    p[d * 11 + 1 + s] = fmaf(jr, sd[d * 10 + s], p[d * 11 + 1 + s]);
        }
#pragma unroll
        for (int k = 0; k < 33; ++k) {
            float x = p[k];
            for (int off = 32; off > 0; off >>= 1) x += __shfl_down(x, off);
            p[k] = x;
        }
        if ((tid & 63) == 0) {
#pragma unroll
            for (int k = 0; k < 33; ++k) atomicAdd(&jts[jn * 33 + k], p[k]);
        }
    } else if (bx < JTS_BLOCKS + POSE_BLOCKS) {
        // ---- pose: Rodrigues -> rotT (transposed) + Cb pose coeffs ----
        int idx = (bx - JTS_BLOCKS) * 256 + tid;
        int b = idx / NJ;
        int jn = idx - b * NJ;
        float ax = body_pose[b * 72 + jn * 3 + 0];
        float ay = body_pose[b * 72 + jn * 3 + 1];
        float az = body_pose[b * 72 + jn * 3 + 2];
        float sx = ax + 1e-8f, sy = ay + 1e-8f, sz = az + 1e-8f;
        float angle = sqrtf(sx * sx + sy * sy + sz * sz);
        float inv = 1.f / angle;
        float ux = ax * inv, uy = ay * inv, uz = az * inv;
        float half = 0.5f * angle;
        float cw = cosf(half), sw = sinf(half);
        float qw = cw, qx = sw * ux, qy = sw * uy, qz = sw * uz;
        float qn = sqrtf(qw * qw + qx * qx + qy * qy + qz * qz);
        float qi = 1.f / qn;
        qw *= qi; qx *= qi; qy *= qi; qz *= qi;
        float w2 = qw * qw, x2 = qx * qx, y2 = qy * qy, z2 = qz * qz;
        float wx = qw * qx, wy = qw * qy, wz = qw * qz;
        float xy = qx * qy, xz = qx * qz, yz = qy * qz;
        float r[9];
        r[0] = w2 + x2 - y2 - z2; r[1] = 2.f * (xy - wz); r[2] = 2.f * (wy + xz);
        r[3] = 2.f * (wz + xy);   r[4] = w2 - x2 + y2 - z2; r[5] = 2.f * (yz - wx);
        r[6] = 2.f * (xz - wy);   r[7] = 2.f * (wx + yz);   r[8] = w2 - x2 - y2 + z2;
#pragma unroll
        for (int k = 0; k < 9; ++k) rotT[(jn * 9 + k) * BATCH + b] = r[k];
        if (jn > 0) {
#pragma unroll
            for (int k = 0; k < 9; ++k) {
                float diag = (k == 0 || k == 4 || k == 8) ? 1.f : 0.f;
                Cb[(size_t)b * KPAD + (jn - 1) * 9 + k] = f2bf(r[k] - diag);
            }
        }
    } else {
        int idx = (bx - (JTS_BLOCKS + POSE_BLOCKS)) * 256 + tid;
        if (idx < MPAD * 32) {
            // ---- Abf = bf16([posedirs | shapedirs | template | 0]) ----
            int r = idx >> 5, kg = idx & 31;
            int k0 = kg * 8;
            ushort8 o;
#pragma unroll
            for (int e = 0; e < 8; ++e) {
                int k = k0 + e;
                float val = 0.f;
                if (r < MROW) {
                    if (k < NPOSE) val = posedirs[(size_t)r * NPOSE + k];
                    else if (k < NPOSE + NBETA) val = shapedirs[(size_t)r * NBETA + (k - NPOSE)];
                    else if (k == NPOSE + NBETA) val = v_template[r];
                }
                o[e] = f2bf(val);
            }
            *(ushort8*)&Abf[(size_t)r * KPAD + k0] = o;
        } else {
            // ---- wT = bf16(weights^T) [32][6896], zero-padded ----
            int idx2 = idx - MPAD * 32;
            if (idx2 < 32 * 862) {
                int k = idx2 / 862;
                int g = idx2 - k * 862;
                int v0 = g * 8;
                ushort8 o;
#pragma unroll
                for (int e = 0; e < 8; ++e) {
                    int v = v0 + e;
                    float val = (k < NJ && v < NVERT) ? weights[(size_t)v * NJ + k] : 0.f;
                    o[e] = f2bf(val);
                }
                *(ushort8*)&wT[(size_t)k * VPAD16 + v0] = o;
            }
        }
    }
}

// ================= chain kernel: kinematic chain -> relB (bf16, A-frag layout), jtr, Cb tail =======
__global__ __launch_bounds__(64) void chain_kernel(
    const float* __restrict__ betas, const float* __restrict__ trans,
    const float* __restrict__ rotT, const float* __restrict__ jts,
    unsigned short* __restrict__ relB, float* __restrict__ jtr_out,
    unsigned short* __restrict__ Cb)
{
    int b = blockIdx.x * 64 + threadIdx.x;
    constexpr int P[NJ] = {-1, 0, 0, 0, 1, 2, 3, 4, 5, 6, 7, 8, 9, 9, 9, 12, 13, 14, 16, 17, 18, 19, 20, 21};

    float be[NBETA];
#pragma unroll
    for (int s = 0; s < NBETA; ++s) be[s] = betas[b * NBETA + s];
#pragma unroll
    for (int s = 0; s < NBETA; ++s) Cb[(size_t)b * KPAD + NPOSE + s] = f2bf(be[s]);
    Cb[(size_t)b * KPAD + NPOSE + NBETA] = f2bf(1.f);
#pragma unroll
    for (int k = 218; k < 256; k += 2) *(unsigned int*)&Cb[(size_t)b * KPAD + k] = 0u;

    float jj[NJ][3];
#pragma unroll
    for (int jn = 0; jn < NJ; ++jn) {
#pragma unroll
        for (int d = 0; d < 3; ++d) {
            const float* pp = &jts[jn * 33 + d * 11];
            float a = pp[0];
#pragma unroll
            for (int s = 0; s < NBETA; ++s) a += pp[1 + s] * be[s];
            jj[jn][d] = a;
        }
    }

    float tr0 = trans[b * 3 + 0], tr1 = trans[b * 3 + 1], tr2 = trans[b * 3 + 2];

    float res[NJ][12];
    {
#pragma unroll
        for (int m = 0; m < 3; ++m) {
#pragma unroll
            for (int n = 0; n < 3; ++n)
                res[0][m * 4 + n] = rotT[(0 * 9 + m * 3 + n) * BATCH + b];
            res[0][m * 4 + 3] = jj[0][m];
        }
    }
#pragma unroll
    for (int i = 1; i < NJ; ++i) {
        const int p = P[i];
        float R[9];
#pragma unroll
        for (int k = 0; k < 9; ++k) R[k] = rotT[(i * 9 + k) * BATCH + b];
        float tx = jj[i][0] - jj[p][0];
        float ty = jj[i][1] - jj[p][1];
        float tz = jj[i][2] - jj[p][2];
#pragma unroll
        for (int m = 0; m < 3; ++m) {
            float p0 = res[p][m * 4 + 0], p1 = res[p][m * 4 + 1], p2 = res[p][m * 4 + 2], p3 = res[p][m * 4 + 3];
#pragma unroll
            for (int n = 0; n < 3; ++n)
                res[i][m * 4 + n] = p0 * R[0 * 3 + n] + p1 * R[1 * 3 + n] + p2 * R[2 * 3 + n];
            res[i][m * 4 + 3] = p0 * tx + p1 * ty + p2 * tz + p3;
        }
    }

    // outputs: relB[b][16][32] bf16 (A-fragment layout: row = m*4+nc, col = joint), jtr
    unsigned short* rb = relB + (size_t)b * 512;
#pragma unroll
    for (int i = 0; i < NJ; ++i) {
#pragma unroll
        for (int m = 0; m < 3; ++m) {
            float r0 = res[i][m * 4 + 0], r1 = res[i][m * 4 + 1], r2 = res[i][m * 4 + 2], t = res[i][m * 4 + 3];
            float tp = t - (r0 * jj[i][0] + r1 * jj[i][1] + r2 * jj[i][2]);
            rb[(m * 4 + 0) * 32 + i] = f2bf(r0);
            rb[(m * 4 + 1) * 32 + i] = f2bf(r1);
            rb[(m * 4 + 2) * 32 + i] = f2bf(r2);
            rb[(m * 4 + 3) * 32 + i] = f2bf(tp);
            float trm = (m == 0) ? tr0 : ((m == 1) ? tr1 : tr2);
            jtr_out[((size_t)b * NJ + i) * 3 + m] = t + trm;
        }
    }
    // zero pads: rows 12..15 (all j), all rows j 24..31
#pragma unroll
    for (int n = 12; n < 16; ++n)
#pragma unroll
        for (int j = 0; j < 24; j += 2) *(unsigned int*)&rb[n * 32 + j] = 0u;
#pragma unroll
    for (int n = 0; n < 16; ++n)
#pragma unroll
        for (int j = 24; j < 32; j += 2) *(unsigned int*)&rb[n * 32 + j] = 0u;
}

// ================= gemm kernel: vposedT[b][vrow] = Cb @ Abf^T (bf16 MFMA) =================
__global__ __launch_bounds__(256) void gemm_kernel(
    const unsigned short* __restrict__ Cb,   // [512][256] bf16
    const unsigned short* __restrict__ Abf,  // [20736][256] bf16
    unsigned short* __restrict__ vposedT)    // [512][20736] bf16
{
    __shared__ unsigned short sm[16384];
    unsigned short* As = sm;
    unsigned short* Bs = sm + 8192;
    const int tid = threadIdx.x;
    const int lane = tid & 63, wid = tid >> 6;
    const int wm = wid >> 1, wn = wid & 1;
    const int lr = lane & 15, h = lane >> 4;
    const int Nbase = blockIdx.x * 128;
    const int Mbase = blockIdx.y * 128;
    const int srow = lane >> 3;
    const int schunk = lane & 7;

    f32x4 acc[4][4];
#pragma unroll
    for (int mi = 0; mi < 4; ++mi)
#pragma unroll
        for (int ni = 0; ni < 4; ++ni) acc[mi][ni] = f32x4{0.f, 0.f, 0.f, 0.f};

    for (int ks = 0; ks < 4; ++ks) {
        __syncthreads();
#pragma unroll
        for (int q = 0; q < 4; ++q) {
            int rowl = wid * 32 + q * 8 + srow;
            int sc = schunk ^ (rowl & 7);
            const unsigned short* gc = &Cb[(size_t)(Mbase + rowl) * KPAD + ks * 64 + sc * 8];
            const unsigned short* ga = &Abf[(size_t)(Nbase + rowl) * KPAD + ks * 64 + sc * 8];
            gload_lds16(gc, (char*)As + wid * 4096 + q * 1024);
            gload_lds16(ga, (char*)Bs + wid * 4096 + q * 1024);
        }
        __syncthreads();
#pragma unroll
        for (int kk = 0; kk < 2; ++kk) {
            short8 a[4], bfr[4];
#pragma unroll
            for (int mi = 0; mi < 4; ++mi) {
                int row = wm * 64 + mi * 16 + lr;
                int ch = (kk * 4 + h) ^ (row & 7);
                a[mi] = *(const short8*)&As[row * 64 + ch * 8];
            }
#pragma unroll
            for (int ni = 0; ni < 4; ++ni) {
                int row = wn * 64 + ni * 16 + lr;
                int ch = (kk * 4 + h) ^ (row & 7);
                bfr[ni] = *(const short8*)&Bs[row * 64 + ch * 8];
            }
#pragma unroll
            for (int mi = 0; mi < 4; ++mi)
#pragma unroll
                for (int ni = 0; ni < 4; ++ni)
                    acc[mi][ni] = __builtin_amdgcn_mfma_f32_16x16x32_bf16(a[mi], bfr[ni], acc[mi][ni], 0, 0, 0);
        }
    }
#pragma unroll
    for (int mi = 0; mi < 4; ++mi) {
#pragma unroll
        for (int ni = 0; ni < 4; ++ni) {
            int vr = Nbase + wn * 64 + ni * 16 + lr;
#pragma unroll
            for (int r = 0; r < 4; ++r) {
                int bb = Mbase + wm * 64 + mi * 16 + h * 4 + r;
                vposedT[(size_t)bb * MPAD + vr] = f2bf(acc[mi][ni][r]);
            }
        }
    }
}

// ================= skin2 kernel: MFMA LBS, zero LDS =================
// wave: 16 verts x 4 batches. A = relB[b] (rows=(m,n), K=j), B = weights (cols=verts).
// D: col(lane&15)=vert, row(h*4+reg): m=h, n=reg -> lane computes out[b][v][m] directly.
__global__ __launch_bounds__(256) void skin2_kernel(
    const unsigned short* __restrict__ relB,     // [512][16][32] bf16
    const unsigned short* __restrict__ wT,       // [32][6896] bf16
    const unsigned short* __restrict__ vposedT,  // [512][20736] bf16
    const float* __restrict__ trans,
    float* __restrict__ out)
{
    const int tid = threadIdx.x;
    const int lane = tid & 63, wid = tid >> 6;
    const int lr = lane & 15, h = lane >> 4;
    const int vt = blockIdx.x;
    const int b0 = blockIdx.y * 16 + wid * 4;
    const int vglob = vt * 16 + lr;

    short8 wfrag;
#pragma unroll
    for (int e = 0; e < 8; ++e)
        wfrag[e] = (short)wT[(size_t)(h * 8 + e) * VPAD16 + vglob];

    f32x4 acc[4];
#pragma unroll
    for (int bi = 0; bi < 4; ++bi) {
        const short8 afrag = *(const short8*)&relB[((size_t)(b0 + bi) * 16 + lr) * 32 + h * 8];
        acc[bi] = __builtin_amdgcn_mfma_f32_16x16x32_bf16(afrag, wfrag, f32x4{0.f, 0.f, 0.f, 0.f}, 0, 0, 0);
    }

#pragma unroll
    for (int bi = 0; bi < 4; ++bi) {
        int b = b0 + bi;
        const unsigned short* vpp = vposedT + (size_t)b * MPAD + (size_t)vglob * 3;
        float x = bf2f(vpp[0]), y = bf2f(vpp[1]), z = bf2f(vpp[2]);
        float r = fmaf(acc[bi][0], x, fmaf(acc[bi][1], y, fmaf(acc[bi][2], z, acc[bi][3])));
        if (h < 3 && vglob < NVERT) {
            out[((size_t)b * NVERT + vglob) * 3 + h] = r + trans[b * 3 + h];
        }
    }
}

extern "C" void kernel_launch(void* const* d_in, const int* in_sizes, int n_in,
                              void* d_out, int out_size, void* d_ws, size_t ws_size,
                              hipStream_t stream) {
    const float* body_pose  = (const float*)d_in[0];
    const float* betas      = (const float*)d_in[1];
    const float* trans      = (const float*)d_in[2];
    const float* v_template = (const float*)d_in[3];
    const float* shapedirs  = (const float*)d_in[4];
    const float* posedirs   = (const float*)d_in[5];
    const float* Jreg       = (const float*)d_in[6];
    const float* weights    = (const float*)d_in[7];
    float* out = (float*)d_out;
    char* base = (char*)d_ws;

    size_t off = 0;
    auto alloc = [&](size_t bytes) { char* p = base + off; off = (off + bytes + 255) & ~(size_t)255; return p; };
    float* rotT              = (float*)alloc((size_t)NJ * 9 * BATCH * 4);       // 442368
    float* jts               = (float*)alloc(792 * 4);
    unsigned short* relB     = (unsigned short*)alloc((size_t)BATCH * 512 * 2); // 524288
    unsigned short* Cb       = (unsigned short*)alloc((size_t)BATCH * KPAD * 2);
    unsigned short* Abf      = (unsigned short*)alloc((size_t)MPAD * KPAD * 2);
    unsigned short* wT       = (unsigned short*)alloc((size_t)32 * VPAD16 * 2); // 441344
    unsigned short* vposedT  = (unsigned short*)alloc((size_t)BATCH * MPAD * 2);
    float* jtr_out = out + (size_t)BATCH * NVERT * 3;

    hipMemsetAsync(jts, 0, 792 * sizeof(float), stream);

    prep_kernel<<<JTS_BLOCKS + POSE_BLOCKS + CONV_BLOCKS, 256, 0, stream>>>(
        Jreg, v_template, shapedirs, posedirs, weights, body_pose,
        jts, rotT, Cb, Abf, wT);
    chain_kernel<<<BATCH / 64, 64, 0, stream>>>(betas, trans, rotT, jts, relB, jtr_out, Cb);
    gemm_kernel<<<dim3(MPAD / 128, BATCH / 128), 256, 0, stream>>>(Cb, Abf, vposedT);
    skin2_kernel<<<dim3(VT_TILES, BATCH / 16), 256, 0, stream>>>(relB, wT, vposedT, trans, out);
}

// Round 5
// 173.123 us; speedup vs baseline: 4.1782x; 1.0065x over previous
//
#include <hip/hip_runtime.h>

#define BATCH 512
#define NVERT 6890
#define NJ 24
#define NBETA 10
#define NPOSE 207
#define KPAD 256
#define MROW 20670      // NVERT*3
#define MPAD 20736      // 162*128
#define VT_TILES 431    // ceil(NVERT/16)
#define VPAD16 6896     // VT_TILES*16

typedef __attribute__((ext_vector_type(8))) short short8;
typedef __attribute__((ext_vector_type(4))) float f32x4;
typedef __attribute__((ext_vector_type(8))) unsigned short ushort8;

static __device__ __forceinline__ unsigned short f2bf(float x) {
    union { float f; unsigned int u; } v; v.f = x;
    unsigned int r = (v.u + 0x7fffu + ((v.u >> 16) & 1u)) >> 16;
    return (unsigned short)r;
}
static __device__ __forceinline__ float bf2f(unsigned short u) {
    union { unsigned int u; float f; } v; v.u = ((unsigned int)u) << 16;
    return v.f;
}
static __device__ __forceinline__ void gload_lds16(const void* g, void* l) {
    __builtin_amdgcn_global_load_lds((const __attribute__((address_space(1))) void*)g,
                                     (__attribute__((address_space(3))) void*)l, 16, 0, 0);
}

// ================= prep kernel: jts | pose | Abf | wT, branch on blockIdx =================
#define JTS_BLOCKS 192
#define POSE_BLOCKS 48
#define CONV_BLOCKS 2619   // 2592 Abf + 27 wT

__global__ __launch_bounds__(256) void prep_kernel(
    const float* __restrict__ Jreg, const float* __restrict__ v_template,
    const float* __restrict__ shapedirs, const float* __restrict__ posedirs,
    const float* __restrict__ weights, const float* __restrict__ body_pose,
    float* __restrict__ jts, float* __restrict__ rotT,
    unsigned short* __restrict__ Cb, unsigned short* __restrict__ Abf,
    unsigned short* __restrict__ wT)
{
    const int bx = blockIdx.x;
    const int tid = threadIdx.x;

    if (bx < JTS_BLOCKS) {
        // ---- jts: JT/JS = Jreg @ [template|shapedirs] ----
        const int jn = bx >> 3;
        const int Vstart = (bx & 7) * 864;
        const int Vend = min(Vstart + 864, NVERT);
        float p[33];
#pragma unroll
        for (int k = 0; k < 33; ++k) p[k] = 0.f;
        for (int v = Vstart + tid; v < Vend; v += 256) {
            float jr = Jreg[jn * NVERT + v];
            p[0]  = fmaf(jr, v_template[v * 3 + 0], p[0]);
            p[11] = fmaf(jr, v_template[v * 3 + 1], p[11]);
            p[22] = fmaf(jr, v_template[v * 3 + 2], p[22]);
            const float* sb = shapedirs + (size_t)v * 30;
            float sd[30];
#pragma unroll
            for (int q = 0; q < 7; ++q) {
                float4 f = *(const float4*)(sb + q * 4);
                sd[q * 4 + 0] = f.x; sd[q * 4 + 1] = f.y; sd[q * 4 + 2] = f.z; sd[q * 4 + 3] = f.w;
            }
            sd[28] = sb[28]; sd[29] = sb[29];
#pragma unroll
            for (int d = 0; d < 3; ++d)
#pragma unroll
                for (int s = 0; s < NBETA; ++s)
                    p[d * 11 + 1 + s] = fmaf(jr, sd[d * 10 + s], p[d * 11 + 1 + s]);
        }
#pragma unroll
        for (int k = 0; k < 33; ++k) {
            float x = p[k];
            for (int off = 32; off > 0; off >>= 1) x += __shfl_down(x, off);
            p[k] = x;
        }
        if ((tid & 63) == 0) {
#pragma unroll
            for (int k = 0; k < 33; ++k) atomicAdd(&jts[jn * 33 + k], p[k]);
        }
    } else if (bx < JTS_BLOCKS + POSE_BLOCKS) {
        // ---- pose: Rodrigues -> rotT (transposed) + Cb pose coeffs ----
        int idx = (bx - JTS_BLOCKS) * 256 + tid;
        int b = idx / NJ;
        int jn = idx - b * NJ;
        float ax = body_pose[b * 72 + jn * 3 + 0];
        float ay = body_pose[b * 72 + jn * 3 + 1];
        float az = body_pose[b * 72 + jn * 3 + 2];
        float sx = ax + 1e-8f, sy = ay + 1e-8f, sz = az + 1e-8f;
        float angle = sqrtf(sx * sx + sy * sy + sz * sz);
        float inv = 1.f / angle;
        float ux = ax * inv, uy = ay * inv, uz = az * inv;
        float half = 0.5f * angle;
        float cw = cosf(half), sw = sinf(half);
        float qw = cw, qx = sw * ux, qy = sw * uy, qz = sw * uz;
        float qn = sqrtf(qw * qw + qx * qx + qy * qy + qz * qz);
        float qi = 1.f / qn;
        qw *= qi; qx *= qi; qy *= qi; qz *= qi;
        float w2 = qw * qw, x2 = qx * qx, y2 = qy * qy, z2 = qz * qz;
        float wx = qw * qx, wy = qw * qy, wz = qw * qz;
        float xy = qx * qy, xz = qx * qz, yz = qy * qz;
        float r[9];
        r[0] = w2 + x2 - y2 - z2; r[1] = 2.f * (xy - wz); r[2] = 2.f * (wy + xz);
        r[3] = 2.f * (wz + xy);   r[4] = w2 - x2 + y2 - z2; r[5] = 2.f * (yz - wx);
        r[6] = 2.f * (xz - wy);   r[7] = 2.f * (wx + yz);   r[8] = w2 - x2 - y2 + z2;
#pragma unroll
        for (int k = 0; k < 9; ++k) rotT[(jn * 9 + k) * BATCH + b] = r[k];
        if (jn > 0) {
#pragma unroll
            for (int k = 0; k < 9; ++k) {
                float diag = (k == 0 || k == 4 || k == 8) ? 1.f : 0.f;
                Cb[(size_t)b * KPAD + (jn - 1) * 9 + k] = f2bf(r[k] - diag);
            }
        }
    } else {
        int idx = (bx - (JTS_BLOCKS + POSE_BLOCKS)) * 256 + tid;
        if (idx < MPAD * 32) {
            // ---- Abf = bf16([posedirs | shapedirs | template | 0]) ----
            int r = idx >> 5, kg = idx & 31;
            int k0 = kg * 8;
            ushort8 o;
            if (r < MROW && k0 + 7 < NPOSE) {
                const float* pp = posedirs + (size_t)r * NPOSE + k0;
                float4 f0 = *(const float4*)pp;
                float4 f1 = *(const float4*)(pp + 4);
                o[0] = f2bf(f0.x); o[1] = f2bf(f0.y); o[2] = f2bf(f0.z); o[3] = f2bf(f0.w);
                o[4] = f2bf(f1.x); o[5] = f2bf(f1.y); o[6] = f2bf(f1.z); o[7] = f2bf(f1.w);
            } else {
#pragma unroll
                for (int e = 0; e < 8; ++e) {
                    int k = k0 + e;
                    float val = 0.f;
                    if (r < MROW) {
                        if (k < NPOSE) val = posedirs[(size_t)r * NPOSE + k];
                        else if (k < NPOSE + NBETA) val = shapedirs[(size_t)r * NBETA + (k - NPOSE)];
                        else if (k == NPOSE + NBETA) val = v_template[r];
                    }
                    o[e] = f2bf(val);
                }
            }
            *(ushort8*)&Abf[(size_t)r * KPAD + k0] = o;
        } else {
            // ---- wT[v][32] = bf16(weights[v][j]), j-padded to 32, v-padded to VPAD16 ----
            int v = idx - MPAD * 32;
            if (v < VPAD16) {
                float wv[24];
                if (v < NVERT) {
                    const float* wp = weights + (size_t)v * NJ;
#pragma unroll
                    for (int q = 0; q < 6; ++q) {
                        float4 f = *(const float4*)(wp + q * 4);
                        wv[q * 4 + 0] = f.x; wv[q * 4 + 1] = f.y; wv[q * 4 + 2] = f.z; wv[q * 4 + 3] = f.w;
                    }
                } else {
#pragma unroll
                    for (int q = 0; q < 24; ++q) wv[q] = 0.f;
                }
                ushort8 o[4];
#pragma unroll
                for (int e = 0; e < 32; ++e)
                    o[e >> 3][e & 7] = (e < 24) ? f2bf(wv[e]) : (unsigned short)0;
#pragma unroll
                for (int q = 0; q < 4; ++q)
                    *(ushort8*)&wT[(size_t)v * 32 + q * 8] = o[q];
            }
        }
    }
}

// ================= chain kernel: kinematic chain -> relB (A-frag layout), jtr, Cb tail =======
// write-out inlined per joint to keep register liveness bounded (no scratch spills)
__global__ __launch_bounds__(64) void chain_kernel(
    const float* __restrict__ betas, const float* __restrict__ trans,
    const float* __restrict__ rotT, const float* __restrict__ jts,
    unsigned short* __restrict__ relB, float* __restrict__ jtr_out,
    unsigned short* __restrict__ Cb)
{
    int b = blockIdx.x * 64 + threadIdx.x;
    constexpr int P[NJ] = {-1, 0, 0, 0, 1, 2, 3, 4, 5, 6, 7, 8, 9, 9, 9, 12, 13, 14, 16, 17, 18, 19, 20, 21};

    float be[NBETA];
#pragma unroll
    for (int s = 0; s < NBETA; ++s) be[s] = betas[b * NBETA + s];
#pragma unroll
    for (int s = 0; s < NBETA; ++s) Cb[(size_t)b * KPAD + NPOSE + s] = f2bf(be[s]);
    Cb[(size_t)b * KPAD + NPOSE + NBETA] = f2bf(1.f);
#pragma unroll
    for (int k = 218; k < 256; k += 2) *(unsigned int*)&Cb[(size_t)b * KPAD + k] = 0u;

    float jj[NJ][3];
#pragma unroll
    for (int jn = 0; jn < NJ; ++jn) {
#pragma unroll
        for (int d = 0; d < 3; ++d) {
            const float* pp = &jts[jn * 33 + d * 11];
            float a = pp[0];
#pragma unroll
            for (int s = 0; s < NBETA; ++s) a += pp[1 + s] * be[s];
            jj[jn][d] = a;
        }
    }

    float tr0 = trans[b * 3 + 0], tr1 = trans[b * 3 + 1], tr2 = trans[b * 3 + 2];
    unsigned short* rb = relB + (size_t)b * 512;

    float res[NJ][12];
#pragma unroll
    for (int i = 0; i < NJ; ++i) {
        if (i == 0) {
#pragma unroll
            for (int m = 0; m < 3; ++m) {
#pragma unroll
                for (int n = 0; n < 3; ++n)
                    res[0][m * 4 + n] = rotT[(m * 3 + n) * BATCH + b];
                res[0][m * 4 + 3] = jj[0][m];
            }
        } else {
            const int p = P[i];
            float R[9];
#pragma unroll
            for (int k = 0; k < 9; ++k) R[k] = rotT[(i * 9 + k) * BATCH + b];
            float tx = jj[i][0] - jj[p][0];
            float ty = jj[i][1] - jj[p][1];
            float tz = jj[i][2] - jj[p][2];
#pragma unroll
            for (int m = 0; m < 3; ++m) {
                float p0 = res[p][m * 4 + 0], p1 = res[p][m * 4 + 1], p2 = res[p][m * 4 + 2], p3 = res[p][m * 4 + 3];
#pragma unroll
                for (int n = 0; n < 3; ++n)
                    res[i][m * 4 + n] = p0 * R[0 * 3 + n] + p1 * R[1 * 3 + n] + p2 * R[2 * 3 + n];
                res[i][m * 4 + 3] = p0 * tx + p1 * ty + p2 * tz + p3;
            }
        }
        // immediate write-out (frees liveness of res[i] once children done)
#pragma unroll
        for (int m = 0; m < 3; ++m) {
            float r0 = res[i][m * 4 + 0], r1 = res[i][m * 4 + 1], r2 = res[i][m * 4 + 2], t = res[i][m * 4 + 3];
            float tp = t - (r0 * jj[i][0] + r1 * jj[i][1] + r2 * jj[i][2]);
            rb[(m * 4 + 0) * 32 + i] = f2bf(r0);
            rb[(m * 4 + 1) * 32 + i] = f2bf(r1);
            rb[(m * 4 + 2) * 32 + i] = f2bf(r2);
            rb[(m * 4 + 3) * 32 + i] = f2bf(tp);
            float trm = (m == 0) ? tr0 : ((m == 1) ? tr1 : tr2);
            jtr_out[((size_t)b * NJ + i) * 3 + m] = t + trm;
        }
    }
    // zero pads: rows 12..15 (all j), all rows j 24..31
#pragma unroll
    for (int n = 12; n < 16; ++n)
#pragma unroll
        for (int j = 0; j < 24; j += 2) *(unsigned int*)&rb[n * 32 + j] = 0u;
#pragma unroll
    for (int n = 0; n < 16; ++n)
#pragma unroll
        for (int j = 24; j < 32; j += 2) *(unsigned int*)&rb[n * 32 + j] = 0u;
}

// ================= gemm kernel: vposedT[b][vrow] = Cb @ Abf^T (bf16 MFMA, 2-phase dbuf) ========
__global__ __launch_bounds__(256) void gemm_kernel(
    const unsigned short* __restrict__ Cb,   // [512][256] bf16
    const unsigned short* __restrict__ Abf,  // [20736][256] bf16
    unsigned short* __restrict__ vposedT)    // [512][20736] bf16
{
    __shared__ unsigned short sm[32768];     // 64KB: 2 x (As 8192 | Bs 8192)
    const int tid = threadIdx.x;
    const int lane = tid & 63, wid = tid >> 6;
    const int wm = wid >> 1, wn = wid & 1;
    const int lr = lane & 15, h = lane >> 4;
    const int Nbase = blockIdx.x * 128;
    const int Mbase = blockIdx.y * 128;
    const int srow = lane >> 3;
    const int schunk = lane & 7;

    f32x4 acc[4][4];
#pragma unroll
    for (int mi = 0; mi < 4; ++mi)
#pragma unroll
        for (int ni = 0; ni < 4; ++ni) acc[mi][ni] = f32x4{0.f, 0.f, 0.f, 0.f};

    auto stage = [&](int buf, int ks) {
        unsigned short* As = sm + buf * 16384;
        unsigned short* Bs = As + 8192;
#pragma unroll
        for (int q = 0; q < 4; ++q) {
            int rowl = wid * 32 + q * 8 + srow;
            int sc = schunk ^ (rowl & 7);
            const unsigned short* gc = &Cb[(size_t)(Mbase + rowl) * KPAD + ks * 64 + sc * 8];
            const unsigned short* ga = &Abf[(size_t)(Nbase + rowl) * KPAD + ks * 64 + sc * 8];
            gload_lds16(gc, (char*)As + wid * 4096 + q * 1024);
            gload_lds16(ga, (char*)Bs + wid * 4096 + q * 1024);
        }
    };

    stage(0, 0);
    __syncthreads();   // drains vmcnt before barrier (compiler-inserted)

    for (int ks = 0; ks < 4; ++ks) {
        const int buf = ks & 1;
        if (ks < 3) stage(buf ^ 1, ks + 1);   // prefetch next tile while computing this one
        unsigned short* As = sm + buf * 16384;
        unsigned short* Bs = As + 8192;
#pragma unroll
        for (int kk = 0; kk < 2; ++kk) {
            short8 a[4], bfr[4];
#pragma unroll
            for (int mi = 0; mi < 4; ++mi) {
                int row = wm * 64 + mi * 16 + lr;
                int ch = (kk * 4 + h) ^ (row & 7);
                a[mi] = *(const short8*)&As[row * 64 + ch * 8];
            }
#pragma unroll
            for (int ni = 0; ni < 4; ++ni) {
                int row = wn * 64 + ni * 16 + lr;
                int ch = (kk * 4 + h) ^ (row & 7);
                bfr[ni] = *(const short8*)&Bs[row * 64 + ch * 8];
            }
#pragma unroll
            for (int mi = 0; mi < 4; ++mi)
#pragma unroll
                for (int ni = 0; ni < 4; ++ni)
                    acc[mi][ni] = __builtin_amdgcn_mfma_f32_16x16x32_bf16(a[mi], bfr[ni], acc[mi][ni], 0, 0, 0);
        }
        __syncthreads();
    }

#pragma unroll
    for (int mi = 0; mi < 4; ++mi) {
#pragma unroll
        for (int ni = 0; ni < 4; ++ni) {
            int vr = Nbase + wn * 64 + ni * 16 + lr;
#pragma unroll
            for (int r = 0; r < 4; ++r) {
                int bb = Mbase + wm * 64 + mi * 16 + h * 4 + r;
                vposedT[(size_t)bb * MPAD + vr] = f2bf(acc[mi][ni][r]);
            }
        }
    }
}

// ================= skin2 kernel: MFMA LBS, zero LDS =================
__global__ __launch_bounds__(256) void skin2_kernel(
    const unsigned short* __restrict__ relB,     // [512][16][32] bf16
    const unsigned short* __restrict__ wT,       // [6896][32] bf16 (B-frag contiguous)
    const unsigned short* __restrict__ vposedT,  // [512][20736] bf16
    const float* __restrict__ trans,
    float* __restrict__ out)
{
    const int tid = threadIdx.x;
    const int lane = tid & 63, wid = tid >> 6;
    const int lr = lane & 15, h = lane >> 4;
    const int vt = blockIdx.x;
    const int b0 = blockIdx.y * 16 + wid * 4;
    const int vglob = vt * 16 + lr;

    const short8 wfrag = *(const short8*)&wT[(size_t)vglob * 32 + h * 8];

    f32x4 acc[4];
#pragma unroll
    for (int bi = 0; bi < 4; ++bi) {
        const short8 afrag = *(const short8*)&relB[((size_t)(b0 + bi) * 16 + lr) * 32 + h * 8];
        acc[bi] = __builtin_amdgcn_mfma_f32_16x16x32_bf16(afrag, wfrag, f32x4{0.f, 0.f, 0.f, 0.f}, 0, 0, 0);
    }

#pragma unroll
    for (int bi = 0; bi < 4; ++bi) {
        int b = b0 + bi;
        const unsigned short* vpp = vposedT + (size_t)b * MPAD + (size_t)vglob * 3;
        float x = bf2f(vpp[0]), y = bf2f(vpp[1]), z = bf2f(vpp[2]);
        float r = fmaf(acc[bi][0], x, fmaf(acc[bi][1], y, fmaf(acc[bi][2], z, acc[bi][3])));
        if (h < 3 && vglob < NVERT) {
            out[((size_t)b * NVERT + vglob) * 3 + h] = r + trans[b * 3 + h];
        }
    }
}

extern "C" void kernel_launch(void* const* d_in, const int* in_sizes, int n_in,
                              void* d_out, int out_size, void* d_ws, size_t ws_size,
                              hipStream_t stream) {
    const float* body_pose  = (const float*)d_in[0];
    const float* betas      = (const float*)d_in[1];
    const float* trans      = (const float*)d_in[2];
    const float* v_template = (const float*)d_in[3];
    const float* shapedirs  = (const float*)d_in[4];
    const float* posedirs   = (const float*)d_in[5];
    const float* Jreg       = (const float*)d_in[6];
    const float* weights    = (const float*)d_in[7];
    float* out = (float*)d_out;
    char* base = (char*)d_ws;

    size_t off = 0;
    auto alloc = [&](size_t bytes) { char* p = base + off; off = (off + bytes + 255) & ~(size_t)255; return p; };
    float* rotT              = (float*)alloc((size_t)NJ * 9 * BATCH * 4);
    float* jts               = (float*)alloc(792 * 4);
    unsigned short* relB     = (unsigned short*)alloc((size_t)BATCH * 512 * 2);
    unsigned short* Cb       = (unsigned short*)alloc((size_t)BATCH * KPAD * 2);
    unsigned short* Abf      = (unsigned short*)alloc((size_t)MPAD * KPAD * 2);
    unsigned short* wT       = (unsigned short*)alloc((size_t)VPAD16 * 32 * 2);
    unsigned short* vposedT  = (unsigned short*)alloc((size_t)BATCH * MPAD * 2);
    float* jtr_out = out + (size_t)BATCH * NVERT * 3;

    hipMemsetAsync(jts, 0, 792 * sizeof(float), stream);

    prep_kernel<<<JTS_BLOCKS + POSE_BLOCKS + CONV_BLOCKS, 256, 0, stream>>>(
        Jreg, v_template, shapedirs, posedirs, weights, body_pose,
        jts, rotT, Cb, Abf, wT);
    chain_kernel<<<BATCH / 64, 64, 0, stream>>>(betas, trans, rotT, jts, relB, jtr_out, Cb);
    gemm_kernel<<<dim3(MPAD / 128, BATCH / 128), 256, 0, stream>>>(Cb, Abf, vposedT);
    skin2_kernel<<<dim3(VT_TILES, BATCH / 16), 256, 0, stream>>>(relB, wT, vposedT, trans, out);
}

// Round 6
// 166.367 us; speedup vs baseline: 4.3479x; 1.0406x over previous
//
#include <hip/hip_runtime.h>

#define BATCH 512
#define NVERT 6890
#define NJ 24
#define NBETA 10
#define NPOSE 207
#define KPAD 256
#define MROW 20670      // NVERT*3
#define MPAD 20736      // 108*192
#define VPADW 6912      // 108*64 verts (wT padding)

typedef __attribute__((ext_vector_type(8))) short short8;
typedef __attribute__((ext_vector_type(4))) float f32x4;
typedef __attribute__((ext_vector_type(8))) unsigned short ushort8;

static __device__ __forceinline__ unsigned short f2bf(float x) {
    union { float f; unsigned int u; } v; v.f = x;
    unsigned int r = (v.u + 0x7fffu + ((v.u >> 16) & 1u)) >> 16;
    return (unsigned short)r;
}
static __device__ __forceinline__ float bf2f(unsigned short u) {
    union { unsigned int u; float f; } v; v.u = ((unsigned int)u) << 16;
    return v.f;
}
static __device__ __forceinline__ void gload_lds16(const void* g, void* l) {
    __builtin_amdgcn_global_load_lds((const __attribute__((address_space(1))) void*)g,
                                     (__attribute__((address_space(3))) void*)l, 16, 0, 0);
}

// ================= prep kernel: jts | pose | Abf | wT, branch on blockIdx =================
#define JTS_BLOCKS 192
#define POSE_BLOCKS 48
#define CONV_BLOCKS 2619   // 2592 Abf + 27 wT

__global__ __launch_bounds__(256) void prep_kernel(
    const float* __restrict__ Jreg, const float* __restrict__ v_template,
    const float* __restrict__ shapedirs, const float* __restrict__ posedirs,
    const float* __restrict__ weights, const float* __restrict__ body_pose,
    float* __restrict__ jts, float* __restrict__ rotT,
    unsigned short* __restrict__ Cb, unsigned short* __restrict__ Abf,
    unsigned short* __restrict__ wT)
{
    const int bx = blockIdx.x;
    const int tid = threadIdx.x;

    if (bx < JTS_BLOCKS) {
        const int jn = bx >> 3;
        const int Vstart = (bx & 7) * 864;
        const int Vend = min(Vstart + 864, NVERT);
        float p[33];
#pragma unroll
        for (int k = 0; k < 33; ++k) p[k] = 0.f;
        for (int v = Vstart + tid; v < Vend; v += 256) {
            float jr = Jreg[jn * NVERT + v];
            p[0]  = fmaf(jr, v_template[v * 3 + 0], p[0]);
            p[11] = fmaf(jr, v_template[v * 3 + 1], p[11]);
            p[22] = fmaf(jr, v_template[v * 3 + 2], p[22]);
            const float* sb = shapedirs + (size_t)v * 30;
            float sd[30];
#pragma unroll
            for (int q = 0; q < 7; ++q) {
                float4 f = *(const float4*)(sb + q * 4);
                sd[q * 4 + 0] = f.x; sd[q * 4 + 1] = f.y; sd[q * 4 + 2] = f.z; sd[q * 4 + 3] = f.w;
            }
            sd[28] = sb[28]; sd[29] = sb[29];
#pragma unroll
            for (int d = 0; d < 3; ++d)
#pragma unroll
                for (int s = 0; s < NBETA; ++s)
                    p[d * 11 + 1 + s] = fmaf(jr, sd[d * 10 + s], p[d * 11 + 1 + s]);
        }
#pragma unroll
        for (int k = 0; k < 33; ++k) {
            float x = p[k];
            for (int off = 32; off > 0; off >>= 1) x += __shfl_down(x, off);
            p[k] = x;
        }
        if ((tid & 63) == 0) {
#pragma unroll
            for (int k = 0; k < 33; ++k) atomicAdd(&jts[jn * 33 + k], p[k]);
        }
    } else if (bx < JTS_BLOCKS + POSE_BLOCKS) {
        int idx = (bx - JTS_BLOCKS) * 256 + tid;
        int b = idx / NJ;
        int jn = idx - b * NJ;
        float ax = body_pose[b * 72 + jn * 3 + 0];
        float ay = body_pose[b * 72 + jn * 3 + 1];
        float az = body_pose[b * 72 + jn * 3 + 2];
        float sx = ax + 1e-8f, sy = ay + 1e-8f, sz = az + 1e-8f;
        float angle = sqrtf(sx * sx + sy * sy + sz * sz);
        float inv = 1.f / angle;
        float ux = ax * inv, uy = ay * inv, uz = az * inv;
        float half = 0.5f * angle;
        float cw = cosf(half), sw = sinf(half);
        float qw = cw, qx = sw * ux, qy = sw * uy, qz = sw * uz;
        float qn = sqrtf(qw * qw + qx * qx + qy * qy + qz * qz);
        float qi = 1.f / qn;
        qw *= qi; qx *= qi; qy *= qi; qz *= qi;
        float w2 = qw * qw, x2 = qx * qx, y2 = qy * qy, z2 = qz * qz;
        float wx = qw * qx, wy = qw * qy, wz = qw * qz;
        float xy = qx * qy, xz = qx * qz, yz = qy * qz;
        float r[9];
        r[0] = w2 + x2 - y2 - z2; r[1] = 2.f * (xy - wz); r[2] = 2.f * (wy + xz);
        r[3] = 2.f * (wz + xy);   r[4] = w2 - x2 + y2 - z2; r[5] = 2.f * (yz - wx);
        r[6] = 2.f * (xz - wy);   r[7] = 2.f * (wx + yz);   r[8] = w2 - x2 - y2 + z2;
#pragma unroll
        for (int k = 0; k < 9; ++k) rotT[(jn * 9 + k) * BATCH + b] = r[k];
        if (jn > 0) {
#pragma unroll
            for (int k = 0; k < 9; ++k) {
                float diag = (k == 0 || k == 4 || k == 8) ? 1.f : 0.f;
                Cb[(size_t)b * KPAD + (jn - 1) * 9 + k] = f2bf(r[k] - diag);
            }
        }
    } else {
        int idx = (bx - (JTS_BLOCKS + POSE_BLOCKS)) * 256 + tid;
        if (idx < MPAD * 32) {
            int r = idx >> 5, kg = idx & 31;
            int k0 = kg * 8;
            ushort8 o;
            if (r < MROW && k0 + 7 < NPOSE) {
                const float* pp = posedirs + (size_t)r * NPOSE + k0;
                float4 f0 = *(const float4*)pp;
                float4 f1 = *(const float4*)(pp + 4);
                o[0] = f2bf(f0.x); o[1] = f2bf(f0.y); o[2] = f2bf(f0.z); o[3] = f2bf(f0.w);
                o[4] = f2bf(f1.x); o[5] = f2bf(f1.y); o[6] = f2bf(f1.z); o[7] = f2bf(f1.w);
            } else {
#pragma unroll
                for (int e = 0; e < 8; ++e) {
                    int k = k0 + e;
                    float val = 0.f;
                    if (r < MROW) {
                        if (k < NPOSE) val = posedirs[(size_t)r * NPOSE + k];
                        else if (k < NPOSE + NBETA) val = shapedirs[(size_t)r * NBETA + (k - NPOSE)];
                        else if (k == NPOSE + NBETA) val = v_template[r];
                    }
                    o[e] = f2bf(val);
                }
            }
            *(ushort8*)&Abf[(size_t)r * KPAD + k0] = o;
        } else {
            // wT[v][32] = bf16(weights[v][j]), j padded to 32, v padded to VPADW
            int v = idx - MPAD * 32;
            if (v < VPADW) {
                float wv[24];
                if (v < NVERT) {
                    const float* wp = weights + (size_t)v * NJ;
#pragma unroll
                    for (int q = 0; q < 6; ++q) {
                        float4 f = *(const float4*)(wp + q * 4);
                        wv[q * 4 + 0] = f.x; wv[q * 4 + 1] = f.y; wv[q * 4 + 2] = f.z; wv[q * 4 + 3] = f.w;
                    }
                } else {
#pragma unroll
                    for (int q = 0; q < 24; ++q) wv[q] = 0.f;
                }
                ushort8 o[4];
#pragma unroll
                for (int e = 0; e < 32; ++e)
                    o[e >> 3][e & 7] = (e < 24) ? f2bf(wv[e]) : (unsigned short)0;
#pragma unroll
                for (int q = 0; q < 4; ++q)
                    *(ushort8*)&wT[(size_t)v * 32 + q * 8] = o[q];
            }
        }
    }
}

// ================= chain kernel: kinematic chain -> relB (A-frag layout), jtr, Cb tail =======
__global__ __launch_bounds__(64) void chain_kernel(
    const float* __restrict__ betas, const float* __restrict__ trans,
    const float* __restrict__ rotT, const float* __restrict__ jts,
    unsigned short* __restrict__ relB, float* __restrict__ jtr_out,
    unsigned short* __restrict__ Cb)
{
    int b = blockIdx.x * 64 + threadIdx.x;
    constexpr int P[NJ] = {-1, 0, 0, 0, 1, 2, 3, 4, 5, 6, 7, 8, 9, 9, 9, 12, 13, 14, 16, 17, 18, 19, 20, 21};

    float be[NBETA];
#pragma unroll
    for (int s = 0; s < NBETA; ++s) be[s] = betas[b * NBETA + s];
#pragma unroll
    for (int s = 0; s < NBETA; ++s) Cb[(size_t)b * KPAD + NPOSE + s] = f2bf(be[s]);
    Cb[(size_t)b * KPAD + NPOSE + NBETA] = f2bf(1.f);
#pragma unroll
    for (int k = 218; k < 256; k += 2) *(unsigned int*)&Cb[(size_t)b * KPAD + k] = 0u;

    float jj[NJ][3];
#pragma unroll
    for (int jn = 0; jn < NJ; ++jn) {
#pragma unroll
        for (int d = 0; d < 3; ++d) {
            const float* pp = &jts[jn * 33 + d * 11];
            float a = pp[0];
#pragma unroll
            for (int s = 0; s < NBETA; ++s) a += pp[1 + s] * be[s];
            jj[jn][d] = a;
        }
    }

    float tr0 = trans[b * 3 + 0], tr1 = trans[b * 3 + 1], tr2 = trans[b * 3 + 2];
    unsigned short* rb = relB + (size_t)b * 512;

    float res[NJ][12];
#pragma unroll
    for (int i = 0; i < NJ; ++i) {
        if (i == 0) {
#pragma unroll
            for (int m = 0; m < 3; ++m) {
#pragma unroll
                for (int n = 0; n < 3; ++n)
                    res[0][m * 4 + n] = rotT[(m * 3 + n) * BATCH + b];
                res[0][m * 4 + 3] = jj[0][m];
            }
        } else {
            const int p = P[i];
            float R[9];
#pragma unroll
            for (int k = 0; k < 9; ++k) R[k] = rotT[(i * 9 + k) * BATCH + b];
            float tx = jj[i][0] - jj[p][0];
            float ty = jj[i][1] - jj[p][1];
            float tz = jj[i][2] - jj[p][2];
#pragma unroll
            for (int m = 0; m < 3; ++m) {
                float p0 = res[p][m * 4 + 0], p1 = res[p][m * 4 + 1], p2 = res[p][m * 4 + 2], p3 = res[p][m * 4 + 3];
#pragma unroll
                for (int n = 0; n < 3; ++n)
                    res[i][m * 4 + n] = p0 * R[0 * 3 + n] + p1 * R[1 * 3 + n] + p2 * R[2 * 3 + n];
                res[i][m * 4 + 3] = p0 * tx + p1 * ty + p2 * tz + p3;
            }
        }
#pragma unroll
        for (int m = 0; m < 3; ++m) {
            float r0 = res[i][m * 4 + 0], r1 = res[i][m * 4 + 1], r2 = res[i][m * 4 + 2], t = res[i][m * 4 + 3];
            float tp = t - (r0 * jj[i][0] + r1 * jj[i][1] + r2 * jj[i][2]);
            rb[(m * 4 + 0) * 32 + i] = f2bf(r0);
            rb[(m * 4 + 1) * 32 + i] = f2bf(r1);
            rb[(m * 4 + 2) * 32 + i] = f2bf(r2);
            rb[(m * 4 + 3) * 32 + i] = f2bf(tp);
            float trm = (m == 0) ? tr0 : ((m == 1) ? tr1 : tr2);
            jtr_out[((size_t)b * NJ + i) * 3 + m] = t + trm;
        }
    }
#pragma unroll
    for (int n = 12; n < 16; ++n)
#pragma unroll
        for (int j = 0; j < 24; j += 2) *(unsigned int*)&rb[n * 32 + j] = 0u;
#pragma unroll
    for (int n = 0; n < 16; ++n)
#pragma unroll
        for (int j = 24; j < 32; j += 2) *(unsigned int*)&rb[n * 32 + j] = 0u;
}

// ================= fused kernel: pose-GEMM + LBS skinning in one block =================
// tile: BM=64 batches x BN=192 vrows (= 64 whole verts), BK=64, 4 waves (1x4 N-split).
// Phase 1: MFMA GEMM into acc[4][3] per thread. Phase 2: acc -> LDS bf16 [64][200],
// Phase 3: per-wave 16 verts x 64 batches skinning via skin2's MFMA pattern.
__global__ __launch_bounds__(256) void fused_kernel(
    const unsigned short* __restrict__ Cb,    // [512][256] bf16
    const unsigned short* __restrict__ Abf,   // [20736][256] bf16
    const unsigned short* __restrict__ relB,  // [512][16][32] bf16
    const unsigned short* __restrict__ wT,    // [6912][32] bf16
    const float* __restrict__ trans,
    float* __restrict__ out)
{
    __shared__ __align__(16) unsigned short sm[16384];  // 32KB: As[64][64] | Bs[192][64]; reused as VP[64][200]
    unsigned short* As = sm;            // 8KB
    unsigned short* Bs = sm + 4096;     // 24KB
    unsigned short* VP = sm;            // epilogue overlay: [64][200] = 25.6KB

    const int tid = threadIdx.x;
    const int lane = tid & 63, wid = tid >> 6;
    const int lr = lane & 15, h = lane >> 4;
    const int Nbase = blockIdx.x * 192;   // vrow base (vert base = bx*64)
    const int Mbase = blockIdx.y * 64;    // batch base
    const int srow = lane >> 3;           // staging: row-in-8
    const int schunk = lane & 7;

    f32x4 acc[4][3];
#pragma unroll
    for (int mi = 0; mi < 4; ++mi)
#pragma unroll
        for (int ni = 0; ni < 3; ++ni) acc[mi][ni] = f32x4{0.f, 0.f, 0.f, 0.f};

    for (int ks = 0; ks < 4; ++ks) {
        __syncthreads();
        // stage As: 64 rows x 8 chunks = 512 slots, 2/thread
#pragma unroll
        for (int q = 0; q < 2; ++q) {
            int idx = q * 256 + tid;
            int rowl = idx >> 3;
            int sc = (idx & 7) ^ (rowl & 7);
            const unsigned short* gc = &Cb[(size_t)(Mbase + rowl) * KPAD + ks * 64 + sc * 8];
            gload_lds16(gc, (char*)As + q * 4096 + wid * 1024);
        }
        // stage Bs: 192 rows x 8 chunks = 1536 slots, 6/thread
#pragma unroll
        for (int q = 0; q < 6; ++q) {
            int idx = q * 256 + tid;
            int rowl = idx >> 3;
            int sc = (idx & 7) ^ (rowl & 7);
            const unsigned short* ga = &Abf[(size_t)(Nbase + rowl) * KPAD + ks * 64 + sc * 8];
            gload_lds16(ga, (char*)Bs + q * 4096 + wid * 1024);
        }
        __syncthreads();
#pragma unroll
        for (int kk = 0; kk < 2; ++kk) {
            short8 a[4], bfr[3];
#pragma unroll
            for (int mi = 0; mi < 4; ++mi) {
                int row = mi * 16 + lr;
                int ch = (kk * 4 + h) ^ (row & 7);
                a[mi] = *(const short8*)&As[row * 64 + ch * 8];
            }
#pragma unroll
            for (int ni = 0; ni < 3; ++ni) {
                int row = wid * 48 + ni * 16 + lr;
                int ch = (kk * 4 + h) ^ (row & 7);
                bfr[ni] = *(const short8*)&Bs[row * 64 + ch * 8];
            }
#pragma unroll
            for (int mi = 0; mi < 4; ++mi)
#pragma unroll
                for (int ni = 0; ni < 3; ++ni)
                    acc[mi][ni] = __builtin_amdgcn_mfma_f32_16x16x32_bf16(a[mi], bfr[ni], acc[mi][ni], 0, 0, 0);
        }
    }

    // Phase 2: acc -> VP[batch][vrow] bf16, row stride 200
    __syncthreads();
#pragma unroll
    for (int mi = 0; mi < 4; ++mi)
#pragma unroll
        for (int ni = 0; ni < 3; ++ni) {
            int vr = wid * 48 + ni * 16 + lr;
#pragma unroll
            for (int r = 0; r < 4; ++r) {
                int bb = mi * 16 + h * 4 + r;
                VP[bb * 200 + vr] = f2bf(acc[mi][ni][r]);
            }
        }
    __syncthreads();

    // Phase 3: skin. wave wid owns verts [wid*16, wid*16+16), loops 64 batches.
    const int vloc = wid * 16 + lr;            // local vert 0..63
    const int vglob = blockIdx.x * 64 + vloc;
    const short8 wfrag = *(const short8*)&wT[(size_t)vglob * 32 + h * 8];
    const bool wr = (h < 3) && (vglob < NVERT);

    for (int bb = 0; bb < 64; ++bb) {
        const int b = Mbase + bb;
        const short8 afrag = *(const short8*)&relB[((size_t)b * 16 + lr) * 32 + h * 8];
        f32x4 t4 = __builtin_amdgcn_mfma_f32_16x16x32_bf16(afrag, wfrag, f32x4{0.f, 0.f, 0.f, 0.f}, 0, 0, 0);
        float x = bf2f(VP[bb * 200 + vloc * 3 + 0]);
        float y = bf2f(VP[bb * 200 + vloc * 3 + 1]);
        float z = bf2f(VP[bb * 200 + vloc * 3 + 2]);
        float r = fmaf(t4[0], x, fmaf(t4[1], y, fmaf(t4[2], z, t4[3])));
        if (wr) out[((size_t)b * NVERT + vglob) * 3 + h] = r + trans[b * 3 + h];
    }
}

extern "C" void kernel_launch(void* const* d_in, const int* in_sizes, int n_in,
                              void* d_out, int out_size, void* d_ws, size_t ws_size,
                              hipStream_t stream) {
    const float* body_pose  = (const float*)d_in[0];
    const float* betas      = (const float*)d_in[1];
    const float* trans      = (const float*)d_in[2];
    const float* v_template = (const float*)d_in[3];
    const float* shapedirs  = (const float*)d_in[4];
    const float* posedirs   = (const float*)d_in[5];
    const float* Jreg       = (const float*)d_in[6];
    const float* weights    = (const float*)d_in[7];
    float* out = (float*)d_out;
    char* base = (char*)d_ws;

    size_t off = 0;
    auto alloc = [&](size_t bytes) { char* p = base + off; off = (off + bytes + 255) & ~(size_t)255; return p; };
    float* rotT              = (float*)alloc((size_t)NJ * 9 * BATCH * 4);
    float* jts               = (float*)alloc(792 * 4);
    unsigned short* relB     = (unsigned short*)alloc((size_t)BATCH * 512 * 2);
    unsigned short* Cb       = (unsigned short*)alloc((size_t)BATCH * KPAD * 2);
    unsigned short* Abf      = (unsigned short*)alloc((size_t)MPAD * KPAD * 2);
    unsigned short* wT       = (unsigned short*)alloc((size_t)VPADW * 32 * 2);
    float* jtr_out = out + (size_t)BATCH * NVERT * 3;

    hipMemsetAsync(jts, 0, 792 * sizeof(float), stream);

    prep_kernel<<<JTS_BLOCKS + POSE_BLOCKS + CONV_BLOCKS, 256, 0, stream>>>(
        Jreg, v_template, shapedirs, posedirs, weights, body_pose,
        jts, rotT, Cb, Abf, wT);
    chain_kernel<<<BATCH / 64, 64, 0, stream>>>(betas, trans, rotT, jts, relB, jtr_out, Cb);
    fused_kernel<<<dim3(MPAD / 192, BATCH / 64), 256, 0, stream>>>(Cb, Abf, relB, wT, trans, out);
}

// Round 7
// 158.133 us; speedup vs baseline: 4.5743x; 1.0521x over previous
//
#include <hip/hip_runtime.h>

#define BATCH 512
#define NVERT 6890
#define NJ 24
#define NBETA 10
#define NPOSE 207
#define KPAD 256
#define MROW 20670      // NVERT*3
#define MPAD 20736      // 108*192
#define VPADW 6912      // 108*64 verts (wT padding)

typedef __attribute__((ext_vector_type(8))) short short8;
typedef __attribute__((ext_vector_type(4))) float f32x4;
typedef __attribute__((ext_vector_type(8))) unsigned short ushort8;

static __device__ __forceinline__ unsigned short f2bf(float x) {
    union { float f; unsigned int u; } v; v.f = x;
    unsigned int r = (v.u + 0x7fffu + ((v.u >> 16) & 1u)) >> 16;
    return (unsigned short)r;
}
static __device__ __forceinline__ float bf2f(unsigned short u) {
    union { unsigned int u; float f; } v; v.u = ((unsigned int)u) << 16;
    return v.f;
}
static __device__ __forceinline__ void gload_lds16(const void* g, void* l) {
    __builtin_amdgcn_global_load_lds((const __attribute__((address_space(1))) void*)g,
                                     (__attribute__((address_space(3))) void*)l, 16, 0, 0);
}

// ================= prep kernel: jts | pose | Abf | wT, branch on blockIdx =================
#define JTS_BLOCKS 192
#define POSE_BLOCKS 48
#define CONV_BLOCKS 2619   // 2592 Abf + 27 wT

__global__ __launch_bounds__(256) void prep_kernel(
    const float* __restrict__ Jreg, const float* __restrict__ v_template,
    const float* __restrict__ shapedirs, const float* __restrict__ posedirs,
    const float* __restrict__ weights, const float* __restrict__ body_pose,
    float* __restrict__ jts, float* __restrict__ rotT,
    unsigned short* __restrict__ Cb, unsigned short* __restrict__ Abf,
    unsigned short* __restrict__ wT)
{
    const int bx = blockIdx.x;
    const int tid = threadIdx.x;

    if (bx < JTS_BLOCKS) {
        const int jn = bx >> 3;
        const int Vstart = (bx & 7) * 864;
        const int Vend = min(Vstart + 864, NVERT);
        float p[33];
#pragma unroll
        for (int k = 0; k < 33; ++k) p[k] = 0.f;
        for (int v = Vstart + tid; v < Vend; v += 256) {
            float jr = Jreg[jn * NVERT + v];
            p[0]  = fmaf(jr, v_template[v * 3 + 0], p[0]);
            p[11] = fmaf(jr, v_template[v * 3 + 1], p[11]);
            p[22] = fmaf(jr, v_template[v * 3 + 2], p[22]);
            const float* sb = shapedirs + (size_t)v * 30;
            float sd[30];
#pragma unroll
            for (int q = 0; q < 7; ++q) {
                float4 f = *(const float4*)(sb + q * 4);
                sd[q * 4 + 0] = f.x; sd[q * 4 + 1] = f.y; sd[q * 4 + 2] = f.z; sd[q * 4 + 3] = f.w;
            }
            sd[28] = sb[28]; sd[29] = sb[29];
#pragma unroll
            for (int d = 0; d < 3; ++d)
#pragma unroll
                for (int s = 0; s < NBETA; ++s)
                    p[d * 11 + 1 + s] = fmaf(jr, sd[d * 10 + s], p[d * 11 + 1 + s]);
        }
#pragma unroll
        for (int k = 0; k < 33; ++k) {
            float x = p[k];
            for (int off = 32; off > 0; off >>= 1) x += __shfl_down(x, off);
            p[k] = x;
        }
        if ((tid & 63) == 0) {
#pragma unroll
            for (int k = 0; k < 33; ++k) atomicAdd(&jts[jn * 33 + k], p[k]);
        }
    } else if (bx < JTS_BLOCKS + POSE_BLOCKS) {
        int idx = (bx - JTS_BLOCKS) * 256 + tid;
        int b = idx / NJ;
        int jn = idx - b * NJ;
        float ax = body_pose[b * 72 + jn * 3 + 0];
        float ay = body_pose[b * 72 + jn * 3 + 1];
        float az = body_pose[b * 72 + jn * 3 + 2];
        float sx = ax + 1e-8f, sy = ay + 1e-8f, sz = az + 1e-8f;
        float angle = sqrtf(sx * sx + sy * sy + sz * sz);
        float inv = 1.f / angle;
        float ux = ax * inv, uy = ay * inv, uz = az * inv;
        float half = 0.5f * angle;
        float cw = cosf(half), sw = sinf(half);
        float qw = cw, qx = sw * ux, qy = sw * uy, qz = sw * uz;
        float qn = sqrtf(qw * qw + qx * qx + qy * qy + qz * qz);
        float qi = 1.f / qn;
        qw *= qi; qx *= qi; qy *= qi; qz *= qi;
        float w2 = qw * qw, x2 = qx * qx, y2 = qy * qy, z2 = qz * qz;
        float wx = qw * qx, wy = qw * qy, wz = qw * qz;
        float xy = qx * qy, xz = qx * qz, yz = qy * qz;
        float r[9];
        r[0] = w2 + x2 - y2 - z2; r[1] = 2.f * (xy - wz); r[2] = 2.f * (wy + xz);
        r[3] = 2.f * (wz + xy);   r[4] = w2 - x2 + y2 - z2; r[5] = 2.f * (yz - wx);
        r[6] = 2.f * (xz - wy);   r[7] = 2.f * (wx + yz);   r[8] = w2 - x2 - y2 + z2;
#pragma unroll
        for (int k = 0; k < 9; ++k) rotT[(jn * 9 + k) * BATCH + b] = r[k];
        if (jn > 0) {
#pragma unroll
            for (int k = 0; k < 9; ++k) {
                float diag = (k == 0 || k == 4 || k == 8) ? 1.f : 0.f;
                Cb[(size_t)b * KPAD + (jn - 1) * 9 + k] = f2bf(r[k] - diag);
            }
        }
    } else {
        int idx = (bx - (JTS_BLOCKS + POSE_BLOCKS)) * 256 + tid;
        if (idx < MPAD * 32) {
            int r = idx >> 5, kg = idx & 31;
            int k0 = kg * 8;
            ushort8 o;
            if (r < MROW && k0 + 7 < NPOSE) {
                const float* pp = posedirs + (size_t)r * NPOSE + k0;
                float4 f0 = *(const float4*)pp;
                float4 f1 = *(const float4*)(pp + 4);
                o[0] = f2bf(f0.x); o[1] = f2bf(f0.y); o[2] = f2bf(f0.z); o[3] = f2bf(f0.w);
                o[4] = f2bf(f1.x); o[5] = f2bf(f1.y); o[6] = f2bf(f1.z); o[7] = f2bf(f1.w);
            } else {
#pragma unroll
                for (int e = 0; e < 8; ++e) {
                    int k = k0 + e;
                    float val = 0.f;
                    if (r < MROW) {
                        if (k < NPOSE) val = posedirs[(size_t)r * NPOSE + k];
                        else if (k < NPOSE + NBETA) val = shapedirs[(size_t)r * NBETA + (k - NPOSE)];
                        else if (k == NPOSE + NBETA) val = v_template[r];
                    }
                    o[e] = f2bf(val);
                }
            }
            *(ushort8*)&Abf[(size_t)r * KPAD + k0] = o;
        } else {
            int v = idx - MPAD * 32;
            if (v < VPADW) {
                float wv[24];
                if (v < NVERT) {
                    const float* wp = weights + (size_t)v * NJ;
#pragma unroll
                    for (int q = 0; q < 6; ++q) {
                        float4 f = *(const float4*)(wp + q * 4);
                        wv[q * 4 + 0] = f.x; wv[q * 4 + 1] = f.y; wv[q * 4 + 2] = f.z; wv[q * 4 + 3] = f.w;
                    }
                } else {
#pragma unroll
                    for (int q = 0; q < 24; ++q) wv[q] = 0.f;
                }
                ushort8 o[4];
#pragma unroll
                for (int e = 0; e < 32; ++e)
                    o[e >> 3][e & 7] = (e < 24) ? f2bf(wv[e]) : (unsigned short)0;
#pragma unroll
                for (int q = 0; q < 4; ++q)
                    *(ushort8*)&wT[(size_t)v * 32 + q * 8] = o[q];
            }
        }
    }
}

// ================= chain3 kernel: thread = (batch, row m); 64b x 3 rows per block =================
// Row-wise chain: row_m(res_i) = row_m(res_parent) . rel_i  -> only 4 live floats per frontier joint.
__global__ __launch_bounds__(192) void chain3_kernel(
    const float* __restrict__ betas, const float* __restrict__ trans,
    const float* __restrict__ rotT, const float* __restrict__ jts,
    unsigned short* __restrict__ relB, float* __restrict__ jtr_out,
    unsigned short* __restrict__ Cb)
{
    __shared__ float jjS[72 * 64];   // [j*3+d][bl]
    const int tid = threadIdx.x;
    const int bl = tid & 63;
    const int grp = tid >> 6;        // 0..2
    const int Mbase = blockIdx.x * 64;
    const int b = Mbase + bl;
    constexpr int P[NJ] = {-1, 0, 0, 0, 1, 2, 3, 4, 5, 6, 7, 8, 9, 9, 9, 12, 13, 14, 16, 17, 18, 19, 20, 21};

    // ---- phase 1: jj -> LDS (each grp computes 8 joints), Cb tail by grp 0 ----
    {
        float be[NBETA];
#pragma unroll
        for (int s = 0; s < NBETA; ++s) be[s] = betas[b * NBETA + s];
#pragma unroll
        for (int j0 = 0; j0 < 8; ++j0) {
            int jn = grp * 8 + j0;
#pragma unroll
            for (int d = 0; d < 3; ++d) {
                const float* pp = &jts[jn * 33 + d * 11];
                float a = pp[0];
#pragma unroll
                for (int s = 0; s < NBETA; ++s) a = fmaf(pp[1 + s], be[s], a);
                jjS[(jn * 3 + d) * 64 + bl] = a;
            }
        }
        if (grp == 0) {
#pragma unroll
            for (int s = 0; s < NBETA; ++s) Cb[(size_t)b * KPAD + NPOSE + s] = f2bf(be[s]);
            Cb[(size_t)b * KPAD + NPOSE + NBETA] = f2bf(1.f);
#pragma unroll
            for (int k = 218; k < 256; k += 2) *(unsigned int*)&Cb[(size_t)b * KPAD + k] = 0u;
        }
    }
    __syncthreads();

    // ---- phase 2: row m of the kinematic chain ----
    const int m = grp;
    const float tr = trans[b * 3 + m];
    float rows[NJ][4];               // static-indexed; SSA keeps only frontier live
    ushort8 rowbuf[4][3];            // packed bf16 output rows (cols 0..23)

#pragma unroll
    for (int i = 0; i < NJ; ++i) {
        float jx = jjS[(i * 3 + 0) * 64 + bl];
        float jy = jjS[(i * 3 + 1) * 64 + bl];
        float jz = jjS[(i * 3 + 2) * 64 + bl];
        float c0, c1, c2, c3;
        if (i == 0) {
            c0 = rotT[(m * 3 + 0) * BATCH + b];
            c1 = rotT[(m * 3 + 1) * BATCH + b];
            c2 = rotT[(m * 3 + 2) * BATCH + b];
            c3 = (m == 0) ? jx : ((m == 1) ? jy : jz);
        } else {
            const int p = P[i];
            float R[9];
#pragma unroll
            for (int k = 0; k < 9; ++k) R[k] = rotT[(i * 9 + k) * BATCH + b];
            float tx = jx - jjS[(p * 3 + 0) * 64 + bl];
            float ty = jy - jjS[(p * 3 + 1) * 64 + bl];
            float tz = jz - jjS[(p * 3 + 2) * 64 + bl];
            float p0 = rows[p][0], p1 = rows[p][1], p2 = rows[p][2], p3 = rows[p][3];
            c0 = p0 * R[0] + p1 * R[3] + p2 * R[6];
            c1 = p0 * R[1] + p1 * R[4] + p2 * R[7];
            c2 = p0 * R[2] + p1 * R[5] + p2 * R[8];
            c3 = fmaf(p0, tx, fmaf(p1, ty, fmaf(p2, tz, p3)));
        }
        rows[i][0] = c0; rows[i][1] = c1; rows[i][2] = c2; rows[i][3] = c3;
        float tp = c3 - (c0 * jx + c1 * jy + c2 * jz);
        rowbuf[0][i >> 3][i & 7] = f2bf(c0);
        rowbuf[1][i >> 3][i & 7] = f2bf(c1);
        rowbuf[2][i >> 3][i & 7] = f2bf(c2);
        rowbuf[3][i >> 3][i & 7] = f2bf(tp);
        jtr_out[((size_t)b * NJ + i) * 3 + m] = c3 + tr;
    }

    // ---- write-out: 4 rows (m*4+0..3) x 32 cols, vectorized 16B stores ----
    const ushort8 zz = {0, 0, 0, 0, 0, 0, 0, 0};
    unsigned short* rb = relB + (size_t)b * 512 + (size_t)(m * 4) * 32;
#pragma unroll
    for (int r = 0; r < 4; ++r) {
#pragma unroll
        for (int q = 0; q < 3; ++q)
            *(ushort8*)&rb[r * 32 + q * 8] = rowbuf[r][q];
        *(ushort8*)&rb[r * 32 + 24] = zz;
    }
    // pad rows 12..15
    unsigned short* rp = relB + (size_t)b * 512;
#pragma unroll
    for (int q = 0; q < 4; ++q) *(ushort8*)&rp[(12 + m) * 32 + q * 8] = zz;
    if (m == 0) {
#pragma unroll
        for (int q = 0; q < 4; ++q) *(ushort8*)&rp[15 * 32 + q * 8] = zz;
    }
}

// ================= fused kernel: pose-GEMM + LBS skinning in one block =================
__global__ __launch_bounds__(256) void fused_kernel(
    const unsigned short* __restrict__ Cb,    // [512][256] bf16
    const unsigned short* __restrict__ Abf,   // [20736][256] bf16
    const unsigned short* __restrict__ relB,  // [512][16][32] bf16
    const unsigned short* __restrict__ wT,    // [6912][32] bf16
    const float* __restrict__ trans,
    float* __restrict__ out)
{
    __shared__ __align__(16) unsigned short sm[16384];  // As[64][64] | Bs[192][64]; reused as VP[64][200]
    unsigned short* As = sm;
    unsigned short* Bs = sm + 4096;
    unsigned short* VP = sm;

    const int tid = threadIdx.x;
    const int lane = tid & 63, wid = tid >> 6;
    const int lr = lane & 15, h = lane >> 4;
    const int Nbase = blockIdx.x * 192;
    const int Mbase = blockIdx.y * 64;

    f32x4 acc[4][3];
#pragma unroll
    for (int mi = 0; mi < 4; ++mi)
#pragma unroll
        for (int ni = 0; ni < 3; ++ni) acc[mi][ni] = f32x4{0.f, 0.f, 0.f, 0.f};

    for (int ks = 0; ks < 4; ++ks) {
        __syncthreads();
#pragma unroll
        for (int q = 0; q < 2; ++q) {
            int idx = q * 256 + tid;
            int rowl = idx >> 3;
            int sc = (idx & 7) ^ (rowl & 7);
            const unsigned short* gc = &Cb[(size_t)(Mbase + rowl) * KPAD + ks * 64 + sc * 8];
            gload_lds16(gc, (char*)As + q * 4096 + wid * 1024);
        }
#pragma unroll
        for (int q = 0; q < 6; ++q) {
            int idx = q * 256 + tid;
            int rowl = idx >> 3;
            int sc = (idx & 7) ^ (rowl & 7);
            const unsigned short* ga = &Abf[(size_t)(Nbase + rowl) * KPAD + ks * 64 + sc * 8];
            gload_lds16(ga, (char*)Bs + q * 4096 + wid * 1024);
        }
        __syncthreads();
#pragma unroll
        for (int kk = 0; kk < 2; ++kk) {
            short8 a[4], bfr[3];
#pragma unroll
            for (int mi = 0; mi < 4; ++mi) {
                int row = mi * 16 + lr;
                int ch = (kk * 4 + h) ^ (row & 7);
                a[mi] = *(const short8*)&As[row * 64 + ch * 8];
            }
#pragma unroll
            for (int ni = 0; ni < 3; ++ni) {
                int row = wid * 48 + ni * 16 + lr;
                int ch = (kk * 4 + h) ^ (row & 7);
                bfr[ni] = *(const short8*)&Bs[row * 64 + ch * 8];
            }
#pragma unroll
            for (int mi = 0; mi < 4; ++mi)
#pragma unroll
                for (int ni = 0; ni < 3; ++ni)
                    acc[mi][ni] = __builtin_amdgcn_mfma_f32_16x16x32_bf16(a[mi], bfr[ni], acc[mi][ni], 0, 0, 0);
        }
    }

    __syncthreads();
#pragma unroll
    for (int mi = 0; mi < 4; ++mi)
#pragma unroll
        for (int ni = 0; ni < 3; ++ni) {
            int vr = wid * 48 + ni * 16 + lr;
#pragma unroll
            for (int r = 0; r < 4; ++r) {
                int bb = mi * 16 + h * 4 + r;
                VP[bb * 200 + vr] = f2bf(acc[mi][ni][r]);
            }
        }
    __syncthreads();

    const int vloc = wid * 16 + lr;
    const int vglob = blockIdx.x * 64 + vloc;
    const short8 wfrag = *(const short8*)&wT[(size_t)vglob * 32 + h * 8];
    const bool wr = (h < 3) && (vglob < NVERT);

    for (int bb = 0; bb < 64; ++bb) {
        const int b = Mbase + bb;
        const short8 afrag = *(const short8*)&relB[((size_t)b * 16 + lr) * 32 + h * 8];
        f32x4 t4 = __builtin_amdgcn_mfma_f32_16x16x32_bf16(afrag, wfrag, f32x4{0.f, 0.f, 0.f, 0.f}, 0, 0, 0);
        float x = bf2f(VP[bb * 200 + vloc * 3 + 0]);
        float y = bf2f(VP[bb * 200 + vloc * 3 + 1]);
        float z = bf2f(VP[bb * 200 + vloc * 3 + 2]);
        float r = fmaf(t4[0], x, fmaf(t4[1], y, fmaf(t4[2], z, t4[3])));
        if (wr) out[((size_t)b * NVERT + vglob) * 3 + h] = r + trans[b * 3 + h];
    }
}

extern "C" void kernel_launch(void* const* d_in, const int* in_sizes, int n_in,
                              void* d_out, int out_size, void* d_ws, size_t ws_size,
                              hipStream_t stream) {
    const float* body_pose  = (const float*)d_in[0];
    const float* betas      = (const float*)d_in[1];
    const float* trans      = (const float*)d_in[2];
    const float* v_template = (const float*)d_in[3];
    const float* shapedirs  = (const float*)d_in[4];
    const float* posedirs   = (const float*)d_in[5];
    const float* Jreg       = (const float*)d_in[6];
    const float* weights    = (const float*)d_in[7];
    float* out = (float*)d_out;
    char* base = (char*)d_ws;

    size_t off = 0;
    auto alloc = [&](size_t bytes) { char* p = base + off; off = (off + bytes + 255) & ~(size_t)255; return p; };
    float* rotT              = (float*)alloc((size_t)NJ * 9 * BATCH * 4);
    float* jts               = (float*)alloc(792 * 4);
    unsigned short* relB     = (unsigned short*)alloc((size_t)BATCH * 512 * 2);
    unsigned short* Cb       = (unsigned short*)alloc((size_t)BATCH * KPAD * 2);
    unsigned short* Abf      = (unsigned short*)alloc((size_t)MPAD * KPAD * 2);
    unsigned short* wT       = (unsigned short*)alloc((size_t)VPADW * 32 * 2);
    float* jtr_out = out + (size_t)BATCH * NVERT * 3;

    hipMemsetAsync(jts, 0, 792 * sizeof(float), stream);

    prep_kernel<<<JTS_BLOCKS + POSE_BLOCKS + CONV_BLOCKS, 256, 0, stream>>>(
        Jreg, v_template, shapedirs, posedirs, weights, body_pose,
        jts, rotT, Cb, Abf, wT);
    chain3_kernel<<<BATCH / 64, 192, 0, stream>>>(betas, trans, rotT, jts, relB, jtr_out, Cb);
    fused_kernel<<<dim3(MPAD / 192, BATCH / 64), 256, 0, stream>>>(Cb, Abf, relB, wT, trans, out);
}

// Round 8
// 157.920 us; speedup vs baseline: 4.5805x; 1.0013x over previous
//
#include <hip/hip_runtime.h>

#define BATCH 512
#define NVERT 6890
#define NJ 24
#define NBETA 10
#define NPOSE 207
#define KPAD 256
#define MROW 20670      // NVERT*3
#define MPAD 20736      // 108*192
#define VPADW 6912      // 108*64 verts (wT padding)

typedef __attribute__((ext_vector_type(8))) short short8;
typedef __attribute__((ext_vector_type(4))) float f32x4;
typedef __attribute__((ext_vector_type(8))) unsigned short ushort8;

static __device__ __forceinline__ unsigned short f2bf(float x) {
    union { float f; unsigned int u; } v; v.f = x;
    unsigned int r = (v.u + 0x7fffu + ((v.u >> 16) & 1u)) >> 16;
    return (unsigned short)r;
}
static __device__ __forceinline__ float bf2f(unsigned short u) {
    union { unsigned int u; float f; } v; v.u = ((unsigned int)u) << 16;
    return v.f;
}
static __device__ __forceinline__ void gload_lds16(const void* g, void* l) {
    __builtin_amdgcn_global_load_lds((const __attribute__((address_space(1))) void*)g,
                                     (__attribute__((address_space(3))) void*)l, 16, 0, 0);
}

// ================= prep kernel: jts | pose | Abf | wT, branch on blockIdx =================
#define JTS_BLOCKS 192
#define POSE_BLOCKS 48
#define CONV_BLOCKS 2619   // 2592 Abf + 27 wT

__global__ __launch_bounds__(256) void prep_kernel(
    const float* __restrict__ Jreg, const float* __restrict__ v_template,
    const float* __restrict__ shapedirs, const float* __restrict__ posedirs,
    const float* __restrict__ weights, const float* __restrict__ body_pose,
    float* __restrict__ jts, float* __restrict__ rotT,
    unsigned short* __restrict__ Cb, unsigned short* __restrict__ Abf,
    unsigned short* __restrict__ wT)
{
    const int bx = blockIdx.x;
    const int tid = threadIdx.x;

    if (bx < JTS_BLOCKS) {
        const int jn = bx >> 3;
        const int Vstart = (bx & 7) * 864;
        const int Vend = min(Vstart + 864, NVERT);
        float p[33];
#pragma unroll
        for (int k = 0; k < 33; ++k) p[k] = 0.f;
        for (int v = Vstart + tid; v < Vend; v += 256) {
            float jr = Jreg[jn * NVERT + v];
            p[0]  = fmaf(jr, v_template[v * 3 + 0], p[0]);
            p[11] = fmaf(jr, v_template[v * 3 + 1], p[11]);
            p[22] = fmaf(jr, v_template[v * 3 + 2], p[22]);
            const float* sb = shapedirs + (size_t)v * 30;
            float sd[30];
#pragma unroll
            for (int q = 0; q < 7; ++q) {
                float4 f = *(const float4*)(sb + q * 4);
                sd[q * 4 + 0] = f.x; sd[q * 4 + 1] = f.y; sd[q * 4 + 2] = f.z; sd[q * 4 + 3] = f.w;
            }
            sd[28] = sb[28]; sd[29] = sb[29];
#pragma unroll
            for (int d = 0; d < 3; ++d)
#pragma unroll
                for (int s = 0; s < NBETA; ++s)
                    p[d * 11 + 1 + s] = fmaf(jr, sd[d * 10 + s], p[d * 11 + 1 + s]);
        }
#pragma unroll
        for (int k = 0; k < 33; ++k) {
            float x = p[k];
            for (int off = 32; off > 0; off >>= 1) x += __shfl_down(x, off);
            p[k] = x;
        }
        if ((tid & 63) == 0) {
#pragma unroll
            for (int k = 0; k < 33; ++k) atomicAdd(&jts[jn * 33 + k], p[k]);
        }
    } else if (bx < JTS_BLOCKS + POSE_BLOCKS) {
        int idx = (bx - JTS_BLOCKS) * 256 + tid;
        int b = idx / NJ;
        int jn = idx - b * NJ;
        float ax = body_pose[b * 72 + jn * 3 + 0];
        float ay = body_pose[b * 72 + jn * 3 + 1];
        float az = body_pose[b * 72 + jn * 3 + 2];
        float sx = ax + 1e-8f, sy = ay + 1e-8f, sz = az + 1e-8f;
        float angle = sqrtf(sx * sx + sy * sy + sz * sz);
        float inv = 1.f / angle;
        float ux = ax * inv, uy = ay * inv, uz = az * inv;
        float half = 0.5f * angle;
        float cw = cosf(half), sw = sinf(half);
        float qw = cw, qx = sw * ux, qy = sw * uy, qz = sw * uz;
        float qn = sqrtf(qw * qw + qx * qx + qy * qy + qz * qz);
        float qi = 1.f / qn;
        qw *= qi; qx *= qi; qy *= qi; qz *= qi;
        float w2 = qw * qw, x2 = qx * qx, y2 = qy * qy, z2 = qz * qz;
        float wx = qw * qx, wy = qw * qy, wz = qw * qz;
        float xy = qx * qy, xz = qx * qz, yz = qy * qz;
        float r[9];
        r[0] = w2 + x2 - y2 - z2; r[1] = 2.f * (xy - wz); r[2] = 2.f * (wy + xz);
        r[3] = 2.f * (wz + xy);   r[4] = w2 - x2 + y2 - z2; r[5] = 2.f * (yz - wx);
        r[6] = 2.f * (xz - wy);   r[7] = 2.f * (wx + yz);   r[8] = w2 - x2 - y2 + z2;
#pragma unroll
        for (int k = 0; k < 9; ++k) rotT[(jn * 9 + k) * BATCH + b] = r[k];
        if (jn > 0) {
#pragma unroll
            for (int k = 0; k < 9; ++k) {
                float diag = (k == 0 || k == 4 || k == 8) ? 1.f : 0.f;
                Cb[(size_t)b * KPAD + (jn - 1) * 9 + k] = f2bf(r[k] - diag);
            }
        }
    } else {
        int idx = (bx - (JTS_BLOCKS + POSE_BLOCKS)) * 256 + tid;
        if (idx < MPAD * 32) {
            int r = idx >> 5, kg = idx & 31;
            int k0 = kg * 8;
            ushort8 o;
            if (r < MROW && k0 + 7 < NPOSE) {
                const float* pp = posedirs + (size_t)r * NPOSE + k0;
                float4 f0 = *(const float4*)pp;
                float4 f1 = *(const float4*)(pp + 4);
                o[0] = f2bf(f0.x); o[1] = f2bf(f0.y); o[2] = f2bf(f0.z); o[3] = f2bf(f0.w);
                o[4] = f2bf(f1.x); o[5] = f2bf(f1.y); o[6] = f2bf(f1.z); o[7] = f2bf(f1.w);
            } else {
#pragma unroll
                for (int e = 0; e < 8; ++e) {
                    int k = k0 + e;
                    float val = 0.f;
                    if (r < MROW) {
                        if (k < NPOSE) val = posedirs[(size_t)r * NPOSE + k];
                        else if (k < NPOSE + NBETA) val = shapedirs[(size_t)r * NBETA + (k - NPOSE)];
                        else if (k == NPOSE + NBETA) val = v_template[r];
                    }
                    o[e] = f2bf(val);
                }
            }
            *(ushort8*)&Abf[(size_t)r * KPAD + k0] = o;
        } else {
            int v = idx - MPAD * 32;
            if (v < VPADW) {
                float wv[24];
                if (v < NVERT) {
                    const float* wp = weights + (size_t)v * NJ;
#pragma unroll
                    for (int q = 0; q < 6; ++q) {
                        float4 f = *(const float4*)(wp + q * 4);
                        wv[q * 4 + 0] = f.x; wv[q * 4 + 1] = f.y; wv[q * 4 + 2] = f.z; wv[q * 4 + 3] = f.w;
                    }
                } else {
#pragma unroll
                    for (int q = 0; q < 24; ++q) wv[q] = 0.f;
                }
                ushort8 o[4];
#pragma unroll
                for (int e = 0; e < 32; ++e)
                    o[e >> 3][e & 7] = (e < 24) ? f2bf(wv[e]) : (unsigned short)0;
#pragma unroll
                for (int q = 0; q < 4; ++q)
                    *(ushort8*)&wT[(size_t)v * 32 + q * 8] = o[q];
            }
        }
    }
}

// ================= chain3 kernel: thread = (batch, row m); 64b x 3 rows per block =================
// __launch_bounds__(192, 1): min-waves=1 -> full VGPR budget, prevents the spill that made
// R6's chain (VGPR_Count=112 vs ~400 floats live state) a 62us scratch-thrash kernel.
__global__ __launch_bounds__(192, 1) void chain3_kernel(
    const float* __restrict__ betas, const float* __restrict__ trans,
    const float* __restrict__ rotT, const float* __restrict__ jts,
    unsigned short* __restrict__ relB, float* __restrict__ jtr_out,
    unsigned short* __restrict__ Cb)
{
    __shared__ float jjS[72 * 64];   // [j*3+d][bl]
    const int tid = threadIdx.x;
    const int bl = tid & 63;
    const int grp = tid >> 6;        // 0..2
    const int b = blockIdx.x * 64 + bl;
    constexpr int P[NJ] = {-1, 0, 0, 0, 1, 2, 3, 4, 5, 6, 7, 8, 9, 9, 9, 12, 13, 14, 16, 17, 18, 19, 20, 21};

    // ---- phase 1: jj -> LDS (each grp computes 8 joints), Cb tail by grp 0 ----
    {
        float be[NBETA];
#pragma unroll
        for (int s = 0; s < NBETA; ++s) be[s] = betas[b * NBETA + s];
#pragma unroll
        for (int j0 = 0; j0 < 8; ++j0) {
            int jn = grp * 8 + j0;
#pragma unroll
            for (int d = 0; d < 3; ++d) {
                const float* pp = &jts[jn * 33 + d * 11];
                float a = pp[0];
#pragma unroll
                for (int s = 0; s < NBETA; ++s) a = fmaf(pp[1 + s], be[s], a);
                jjS[(jn * 3 + d) * 64 + bl] = a;
            }
        }
        if (grp == 0) {
#pragma unroll
            for (int s = 0; s < NBETA; ++s) Cb[(size_t)b * KPAD + NPOSE + s] = f2bf(be[s]);
            Cb[(size_t)b * KPAD + NPOSE + NBETA] = f2bf(1.f);
#pragma unroll
            for (int k = 218; k < 256; k += 2) *(unsigned int*)&Cb[(size_t)b * KPAD + k] = 0u;
        }
    }
    __syncthreads();

    // ---- phase 2: row m of the kinematic chain; rolling 8-joint output buffers ----
    const int m = grp;
    const float tr = trans[b * 3 + m];
    unsigned short* rb = relB + (size_t)b * 512 + (size_t)(m * 4) * 32;
    float rows[NJ][4];               // static-indexed; frontier liveness ~56 floats
    ushort8 o0, o1, o2, o3;

#pragma unroll
    for (int i = 0; i < NJ; ++i) {
        float jx = jjS[(i * 3 + 0) * 64 + bl];
        float jy = jjS[(i * 3 + 1) * 64 + bl];
        float jz = jjS[(i * 3 + 2) * 64 + bl];
        float c0, c1, c2, c3;
        if (i == 0) {
            c0 = rotT[(m * 3 + 0) * BATCH + b];
            c1 = rotT[(m * 3 + 1) * BATCH + b];
            c2 = rotT[(m * 3 + 2) * BATCH + b];
            c3 = (m == 0) ? jx : ((m == 1) ? jy : jz);
        } else {
            const int p = P[i];
            float R[9];
#pragma unroll
            for (int k = 0; k < 9; ++k) R[k] = rotT[(i * 9 + k) * BATCH + b];
            float tx = jx - jjS[(p * 3 + 0) * 64 + bl];
            float ty = jy - jjS[(p * 3 + 1) * 64 + bl];
            float tz = jz - jjS[(p * 3 + 2) * 64 + bl];
            float p0 = rows[p][0], p1 = rows[p][1], p2 = rows[p][2], p3 = rows[p][3];
            c0 = p0 * R[0] + p1 * R[3] + p2 * R[6];
            c1 = p0 * R[1] + p1 * R[4] + p2 * R[7];
            c2 = p0 * R[2] + p1 * R[5] + p2 * R[8];
            c3 = fmaf(p0, tx, fmaf(p1, ty, fmaf(p2, tz, p3)));
        }
        rows[i][0] = c0; rows[i][1] = c1; rows[i][2] = c2; rows[i][3] = c3;
        float tp = c3 - (c0 * jx + c1 * jy + c2 * jz);
        o0[i & 7] = f2bf(c0);
        o1[i & 7] = f2bf(c1);
        o2[i & 7] = f2bf(c2);
        o3[i & 7] = f2bf(tp);
        jtr_out[((size_t)b * NJ + i) * 3 + m] = c3 + tr;
        if ((i & 7) == 7) {
            const int g = i >> 3;
            *(ushort8*)&rb[0 * 32 + g * 8] = o0;
            *(ushort8*)&rb[1 * 32 + g * 8] = o1;
            *(ushort8*)&rb[2 * 32 + g * 8] = o2;
            *(ushort8*)&rb[3 * 32 + g * 8] = o3;
        }
    }

    // ---- pads: col 24..31 of own 4 rows; rows 12..15 ----
    const ushort8 zz = {0, 0, 0, 0, 0, 0, 0, 0};
#pragma unroll
    for (int r = 0; r < 4; ++r)
        *(ushort8*)&rb[r * 32 + 24] = zz;
    unsigned short* rp = relB + (size_t)b * 512;
#pragma unroll
    for (int q = 0; q < 4; ++q) *(ushort8*)&rp[(12 + m) * 32 + q * 8] = zz;
    if (m == 0) {
#pragma unroll
        for (int q = 0; q < 4; ++q) *(ushort8*)&rp[15 * 32 + q * 8] = zz;
    }
}

// ================= fused kernel: pose-GEMM + LBS skinning in one block =================
__global__ __launch_bounds__(256) void fused_kernel(
    const unsigned short* __restrict__ Cb,    // [512][256] bf16
    const unsigned short* __restrict__ Abf,   // [20736][256] bf16
    const unsigned short* __restrict__ relB,  // [512][16][32] bf16
    const unsigned short* __restrict__ wT,    // [6912][32] bf16
    const float* __restrict__ trans,
    float* __restrict__ out)
{
    __shared__ __align__(16) unsigned short sm[16384];  // As[64][64] | Bs[192][64]; reused as VP[64][200]
    unsigned short* As = sm;
    unsigned short* Bs = sm + 4096;
    unsigned short* VP = sm;

    const int tid = threadIdx.x;
    const int lane = tid & 63, wid = tid >> 6;
    const int lr = lane & 15, h = lane >> 4;
    const int Nbase = blockIdx.x * 192;
    const int Mbase = blockIdx.y * 64;

    f32x4 acc[4][3];
#pragma unroll
    for (int mi = 0; mi < 4; ++mi)
#pragma unroll
        for (int ni = 0; ni < 3; ++ni) acc[mi][ni] = f32x4{0.f, 0.f, 0.f, 0.f};

    for (int ks = 0; ks < 4; ++ks) {
        __syncthreads();
#pragma unroll
        for (int q = 0; q < 2; ++q) {
            int idx = q * 256 + tid;
            int rowl = idx >> 3;
            int sc = (idx & 7) ^ (rowl & 7);
            const unsigned short* gc = &Cb[(size_t)(Mbase + rowl) * KPAD + ks * 64 + sc * 8];
            gload_lds16(gc, (char*)As + q * 4096 + wid * 1024);
        }
#pragma unroll
        for (int q = 0; q < 6; ++q) {
            int idx = q * 256 + tid;
            int rowl = idx >> 3;
            int sc = (idx & 7) ^ (rowl & 7);
            const unsigned short* ga = &Abf[(size_t)(Nbase + rowl) * KPAD + ks * 64 + sc * 8];
            gload_lds16(ga, (char*)Bs + q * 4096 + wid * 1024);
        }
        __syncthreads();
#pragma unroll
        for (int kk = 0; kk < 2; ++kk) {
            short8 a[4], bfr[3];
#pragma unroll
            for (int mi = 0; mi < 4; ++mi) {
                int row = mi * 16 + lr;
                int ch = (kk * 4 + h) ^ (row & 7);
                a[mi] = *(const short8*)&As[row * 64 + ch * 8];
            }
#pragma unroll
            for (int ni = 0; ni < 3; ++ni) {
                int row = wid * 48 + ni * 16 + lr;
                int ch = (kk * 4 + h) ^ (row & 7);
                bfr[ni] = *(const short8*)&Bs[row * 64 + ch * 8];
            }
#pragma unroll
            for (int mi = 0; mi < 4; ++mi)
#pragma unroll
                for (int ni = 0; ni < 3; ++ni)
                    acc[mi][ni] = __builtin_amdgcn_mfma_f32_16x16x32_bf16(a[mi], bfr[ni], acc[mi][ni], 0, 0, 0);
        }
    }

    __syncthreads();
#pragma unroll
    for (int mi = 0; mi < 4; ++mi)
#pragma unroll
        for (int ni = 0; ni < 3; ++ni) {
            int vr = wid * 48 + ni * 16 + lr;
#pragma unroll
            for (int r = 0; r < 4; ++r) {
                int bb = mi * 16 + h * 4 + r;
                VP[bb * 200 + vr] = f2bf(acc[mi][ni][r]);
            }
        }
    __syncthreads();

    const int vloc = wid * 16 + lr;
    const int vglob = blockIdx.x * 64 + vloc;
    const short8 wfrag = *(const short8*)&wT[(size_t)vglob * 32 + h * 8];
    const bool wr = (h < 3) && (vglob < NVERT);

    for (int bb = 0; bb < 64; ++bb) {
        const int b = Mbase + bb;
        const short8 afrag = *(const short8*)&relB[((size_t)b * 16 + lr) * 32 + h * 8];
        f32x4 t4 = __builtin_amdgcn_mfma_f32_16x16x32_bf16(afrag, wfrag, f32x4{0.f, 0.f, 0.f, 0.f}, 0, 0, 0);
        float x = bf2f(VP[bb * 200 + vloc * 3 + 0]);
        float y = bf2f(VP[bb * 200 + vloc * 3 + 1]);
        float z = bf2f(VP[bb * 200 + vloc * 3 + 2]);
        float r = fmaf(t4[0], x, fmaf(t4[1], y, fmaf(t4[2], z, t4[3])));
        if (wr) out[((size_t)b * NVERT + vglob) * 3 + h] = r + trans[b * 3 + h];
    }
}

extern "C" void kernel_launch(void* const* d_in, const int* in_sizes, int n_in,
                              void* d_out, int out_size, void* d_ws, size_t ws_size,
                              hipStream_t stream) {
    const float* body_pose  = (const float*)d_in[0];
    const float* betas      = (const float*)d_in[1];
    const float* trans      = (const float*)d_in[2];
    const float* v_template = (const float*)d_in[3];
    const float* shapedirs  = (const float*)d_in[4];
    const float* posedirs   = (const float*)d_in[5];
    const float* Jreg       = (const float*)d_in[6];
    const float* weights    = (const float*)d_in[7];
    float* out = (float*)d_out;
    char* base = (char*)d_ws;

    size_t off = 0;
    auto alloc = [&](size_t bytes) { char* p = base + off; off = (off + bytes + 255) & ~(size_t)255; return p; };
    float* rotT              = (float*)alloc((size_t)NJ * 9 * BATCH * 4);
    float* jts               = (float*)alloc(792 * 4);
    unsigned short* relB     = (unsigned short*)alloc((size_t)BATCH * 512 * 2);
    unsigned short* Cb       = (unsigned short*)alloc((size_t)BATCH * KPAD * 2);
    unsigned short* Abf      = (unsigned short*)alloc((size_t)MPAD * KPAD * 2);
    unsigned short* wT       = (unsigned short*)alloc((size_t)VPADW * 32 * 2);
    float* jtr_out = out + (size_t)BATCH * NVERT * 3;

    hipMemsetAsync(jts, 0, 792 * sizeof(float), stream);

    prep_kernel<<<JTS_BLOCKS + POSE_BLOCKS + CONV_BLOCKS, 256, 0, stream>>>(
        Jreg, v_template, shapedirs, posedirs, weights, body_pose,
        jts, rotT, Cb, Abf, wT);
    chain3_kernel<<<BATCH / 64, 192, 0, stream>>>(betas, trans, rotT, jts, relB, jtr_out, Cb);
    fused_kernel<<<dim3(MPAD / 192, BATCH / 64), 256, 0, stream>>>(Cb, Abf, relB, wT, trans, out);
}